// Round 14
// baseline (1554.357 us; speedup 1.0000x reference)
//
#include <hip/hip_runtime.h>
#include <hip/hip_bf16.h>
#include <math.h>

#define NEGV -1e9f
#define NEGH -5e8f

typedef __attribute__((ext_vector_type(8))) short short8;
typedef __attribute__((ext_vector_type(4))) float f32x4;

__device__ __forceinline__ unsigned fkey(float f) {
  unsigned u = __float_as_uint(f);
  return (u & 0x80000000u) ? ~u : (u | 0x80000000u);
}
__device__ __forceinline__ unsigned long long key48(float s, int j) {
  return ((unsigned long long)fkey(s) << 15) | (unsigned long long)(32767 - j);
}
__device__ __forceinline__ unsigned short bf16_rne(float v) {
  unsigned u = __float_as_uint(v);
  unsigned r = u + 0x7FFFu + ((u >> 16) & 1u);
  return (unsigned short)(r >> 16);
}
__device__ __forceinline__ float bf16_f(unsigned short h) {
  return __uint_as_float(((unsigned)h) << 16);
}

// ==================================================================
// Packed-tile byte layout (per plane: rowpairs x 128B):
//   byte(row,k) = (row>>1)*128 + ((((row&1)<<6) + 2k) ^ (((row>>1)&7)<<4))
// A-image is now FP32 PAIRS in the same positional order:
//   W1f[((ct*144+s)*2048 + dwimg)*2 + {0,1}] = (w0, w1)
// The split to hi/mid/lo happens IN-KERNEL with the identical
// bf16_rne chain -> LDS bytes identical to the r5-r13 packed planes
// -> conv1 bitwise identical (r11 freeze respected).
// K-order: TAP-MAJOR — FROZEN.
// ==================================================================

// ------------------------------------------------------------------
// Pack W1 -> fp32 pair image (9.4 MB vs 14.2 MB packed: -33% traffic)
// ------------------------------------------------------------------
__global__ __launch_bounds__(256) void w1pack_kernel(
    const float* __restrict__ W1, float* __restrict__ W1f) {
  int g = blockIdx.x * 256 + threadIdx.x;   // 512*256 = 131072 exact
  int oc = g >> 8;
  int cp = g & 255;
  int cin = cp * 2;
  int ct = oc >> 7;
  int row = oc & 127;
  float buf[18];
  const float* src = W1 + (size_t)oc * 4608 + cin * 9;
  #pragma unroll
  for (int i = 0; i < 18; ++i) buf[i] = src[i];
  int k = cin & 31;
  int R = row >> 1;
  int val = ((row & 1) << 6) | (k << 1);
  int tb = (R << 7) | (val ^ ((R & 7) << 4));
  int dwimg = tb >> 2;
  int sBase = cp >> 4;                      // cin>>5
  #pragma unroll
  for (int tap = 0; tap < 9; ++tap) {
    int s = tap * 16 + sBase;               // tap-major (frozen)
    size_t fb = ((size_t)(ct * 144 + s) * 2048 + dwimg) * 2;
    W1f[fb]     = buf[tap];
    W1f[fb + 1] = buf[9 + tap];
  }
}

// ------------------------------------------------------------------
// Heads weight transpose (verbatim r13, verified)
// ------------------------------------------------------------------
__global__ __launch_bounds__(256) void wtpack_kernel(
    const float* __restrict__ Wreg, const float* __restrict__ Wcls,
    float* __restrict__ Wt) {
  int i = blockIdx.x * 256 + threadIdx.x;   // 108*256 = 27648 exact
  int c = i / 54, j = i - c * 54;
  Wt[i] = (j < 36) ? Wreg[j * 512 + c] : Wcls[(j - 36) * 512 + c];
}

// ------------------------------------------------------------------
// Conv 3x3 split-3 bf16 MFMA GEMM. A staged fp32->in-kernel split
// (LDS bytes identical to r5-r13). Single 48KB LDS (r9: dbuf null;
// 3 blocks/CU). ct-grouped block order for L2 weight residency.
// ------------------------------------------------------------------
__global__ __launch_bounds__(256) void conv_mfma_kernel(
    const float* __restrict__ feat, const float* __restrict__ W1f,
    const float* __restrict__ b1, float* __restrict__ conv1) {
  __shared__ char smem[49152];           // A 3x8K | B 3x8K
  const int tid = threadIdx.x;
  const int bid = blockIdx.x;            // 0..639, ct-grouped
  const int ct = bid / 160;
  const int rem = bid - ct * 160;
  const int b  = rem / 20;
  const int n0 = (rem % 20) * 128;
  const int wv = tid >> 6, ln = tid & 63;

  const int spix = tid & 127;
  const int kh   = tid >> 7;
  int p = n0 + spix; if (p > 2499) p = 2499;
  const int pyy = p / 50;
  const int pxx = p - pyy * 50;
  const float* featb = feat + (size_t)b * 512 * 2500;
  const float* wsrc = W1f + (size_t)ct * 144 * 4096;

  const int wch0  = (wv >> 1) * 64;
  const int wpix0 = (wv & 1) * 64;
  const int lrow = ln & 15, lg = ln >> 4;

  f32x4 acc[4][4];
  #pragma unroll
  for (int i = 0; i < 4; ++i)
    #pragma unroll
    for (int j = 0; j < 4; ++j) acc[i][j] = (f32x4)0.f;

  float u[16];    // B prefetch
  float ua[16];   // A prefetch (8 fp32 pairs)

  auto loadFeat = [&](int s) {
    int tap = s >> 4;
    int dy = tap / 3, dx = tap - dy * 3;
    int iy = pyy + dy - 1, ix = pxx + dx - 1;
    bool ok = ((unsigned)iy < 50u) && ((unsigned)ix < 50u);
    int cinb = ((s & 15) << 5) + kh * 16;
    const float* base = featb + (size_t)cinb * 2500 + iy * 50 + ix;
    #pragma unroll
    for (int i = 0; i < 16; ++i) u[i] = ok ? base[(size_t)i * 2500] : 0.f;
  };
  auto loadA = [&](int s) {
    const float* asrc = wsrc + (size_t)s * 4096 + tid * 16;
    #pragma unroll
    for (int i = 0; i < 4; ++i)
      *(float4*)&ua[i * 4] = *(const float4*)(asrc + i * 4);
  };
  auto writeA = [&]() {
    unsigned hw[8], mw[8], lw[8];
    #pragma unroll
    for (int i = 0; i < 8; ++i) {
      float a0 = ua[2 * i], a1 = ua[2 * i + 1];
      unsigned short h0 = bf16_rne(a0), h1 = bf16_rne(a1);
      float r0 = a0 - bf16_f(h0), r1 = a1 - bf16_f(h1);
      unsigned short m0 = bf16_rne(r0), m1 = bf16_rne(r1);
      unsigned short l0 = bf16_rne(r0 - bf16_f(m0));
      unsigned short l1 = bf16_rne(r1 - bf16_f(m1));
      hw[i] = (unsigned)h0 | ((unsigned)h1 << 16);
      mw[i] = (unsigned)m0 | ((unsigned)m1 << 16);
      lw[i] = (unsigned)l0 | ((unsigned)l1 << 16);
    }
    char* base = smem + tid * 32;          // pair p=tid*8.. -> byte p*4
    *(uint4*)(base)              = *(uint4*)&hw[0];
    *(uint4*)(base + 16)         = *(uint4*)&hw[4];
    *(uint4*)(base + 8192)       = *(uint4*)&mw[0];
    *(uint4*)(base + 8192 + 16)  = *(uint4*)&mw[4];
    *(uint4*)(base + 16384)      = *(uint4*)&lw[0];
    *(uint4*)(base + 16384 + 16) = *(uint4*)&lw[4];
  };
  auto writeB = [&]() {
    unsigned short h[16], m[16], l[16];
    #pragma unroll
    for (int i = 0; i < 16; ++i) {
      float v = u[i];
      h[i] = bf16_rne(v);
      float r1 = v - bf16_f(h[i]);
      m[i] = bf16_rne(r1);
      float r2 = r1 - bf16_f(m[i]);
      l[i] = bf16_rne(r2);
    }
    const int r = spix >> 1;
    const int swz = (r & 7) << 4;
    char* rowb = smem + 24576 + r * 128;
    #pragma unroll
    for (int pl = 0; pl < 3; ++pl) {
      const unsigned short* sp = (pl == 0) ? h : (pl == 1 ? m : l);
      char* pb = rowb + pl * 8192;
      #pragma unroll
      for (int q = 0; q < 4; ++q) {
        int pre = ((spix & 1) << 6) + kh * 32 + q * 8;
        uint2 w;
        w.x = (unsigned)sp[q*4]   | ((unsigned)sp[q*4+1] << 16);
        w.y = (unsigned)sp[q*4+2] | ((unsigned)sp[q*4+3] << 16);
        *(uint2*)(pb + (pre ^ swz)) = w;
      }
    }
  };
  auto rdFrag = [&](const char* base, int row) -> short8 {
    int byte = (row >> 1) * 128 +
               ((((row & 1) << 6) + (lg << 4)) ^ (((row >> 1) & 7) << 4));
    return *(const short8*)(base + byte);
  };

  loadA(0);
  loadFeat(0);
  #pragma unroll 1
  for (int s = 0; s < 144; ++s) {
    __syncthreads();                 // previous compute done with LDS
    writeA();
    writeB();
    __syncthreads();                 // staging visible
    if (s + 1 < 144) { loadA(s + 1); loadFeat(s + 1); }  // fly over compute
    short8 fa[3][4];
    #pragma unroll
    for (int pl = 0; pl < 3; ++pl)
      #pragma unroll
      for (int f = 0; f < 4; ++f)
        fa[pl][f] = rdFrag(smem + pl * 8192, wch0 + f * 16 + lrow);
    #pragma unroll
    for (int jb = 0; jb < 3; ++jb) {
      short8 fb[4];
      #pragma unroll
      for (int f = 0; f < 4; ++f)
        fb[f] = rdFrag(smem + 24576 + jb * 8192, wpix0 + f * 16 + lrow);
      const int na = 3 - jb;
      #pragma unroll
      for (int ap = 0; ap < 3; ++ap) {
        if (ap < na) {
          #pragma unroll
          for (int i = 0; i < 4; ++i)
            #pragma unroll
            for (int j = 0; j < 4; ++j)
              acc[i][j] = __builtin_amdgcn_mfma_f32_16x16x32_bf16(
                  fa[ap][i], fb[j], acc[i][j], 0, 0, 0);
        }
      }
    }
  }

  const int chb = ct * 128 + wch0 + lg * 4;
  #pragma unroll
  for (int i = 0; i < 4; ++i) {
    int ch = chb + i * 16;
    float4 bias = *(const float4*)&b1[ch];
    #pragma unroll
    for (int j = 0; j < 4; ++j) {
      int pix = n0 + wpix0 + j * 16 + lrow;
      if (pix < 2500) {
        float4 o;
        o.x = fmaxf(acc[i][j][0] + bias.x, 0.f);
        o.y = fmaxf(acc[i][j][1] + bias.y, 0.f);
        o.z = fmaxf(acc[i][j][2] + bias.z, 0.f);
        o.w = fmaxf(acc[i][j][3] + bias.w, 0.f);
        *(float4*)&conv1[(size_t)(b * 2500 + pix) * 512 + ch] = o;
      }
    }
  }
}

// ------------------------------------------------------------------
// Heads v2 (verbatim r13, verified)
// ------------------------------------------------------------------
__global__ __launch_bounds__(256) void heads_kernel(
    const float* __restrict__ conv1, const float* __restrict__ Wt,
    const float* __restrict__ breg, const float* __restrict__ bcls,
    float* __restrict__ boxes, float* __restrict__ scores) {
  __shared__ float v[16][512];
  __shared__ float o54[16][56];
  const int tid = threadIdx.x;
  const int wvi = tid >> 6, lane = tid & 63;
  const int pix0 = blockIdx.x * 16;
  float4* vf = (float4*)v;
  const float4* src4 = (const float4*)(conv1 + (size_t)pix0 * 512);
  #pragma unroll
  for (int i = 0; i < 8; ++i) vf[i * 256 + tid] = src4[i * 256 + tid];
  __syncthreads();

  if (lane < 54) {
    float s[4][4];
    #pragma unroll
    for (int p = 0; p < 4; ++p)
      #pragma unroll
      for (int q = 0; q < 4; ++q) s[p][q] = 0.f;
    const int pl0 = wvi * 4;
    for (int c = 0; c < 512; c += 4) {
      float w0 = Wt[(c + 0) * 54 + lane];
      float w1 = Wt[(c + 1) * 54 + lane];
      float w2 = Wt[(c + 2) * 54 + lane];
      float w3 = Wt[(c + 3) * 54 + lane];
      #pragma unroll
      for (int p = 0; p < 4; ++p) {
        s[p][0] = fmaf(v[pl0 + p][c],     w0, s[p][0]);
        s[p][1] = fmaf(v[pl0 + p][c + 1], w1, s[p][1]);
        s[p][2] = fmaf(v[pl0 + p][c + 2], w2, s[p][2]);
        s[p][3] = fmaf(v[pl0 + p][c + 3], w3, s[p][3]);
      }
    }
    float bias = (lane < 36) ? breg[lane] : bcls[lane - 36];
    #pragma unroll
    for (int p = 0; p < 4; ++p)
      o54[pl0 + p][lane] = (s[p][0] + s[p][1]) + (s[p][2] + s[p][3]) + bias;
  }
  __syncthreads();

  if (tid < 144) {
    const int pl = tid / 9;
    const int a  = tid - pl * 9;
    const int pix = pix0 + pl;
    const int b = pix / 2500;
    const int n = pix - b * 2500;
    const int y = n / 50, x = n - y * 50;
    float d0 = o54[pl][a * 4 + 0], d1 = o54[pl][a * 4 + 1];
    float d2 = o54[pl][a * 4 + 2], d3 = o54[pl][a * 4 + 3];
    float sc0 = o54[pl][36 + a * 2], sc1 = o54[pl][36 + a * 2 + 1];
    float mx = fmaxf(sc0, sc1);
    float e0 = expf(sc0 - mx), e1 = expf(sc1 - mx);
    float fg = e1 / (e0 + e1);
    const int ri = a / 3;
    const int si = a - ri * 3;
    float sv = (si == 0) ? 8.f : (si == 1 ? 16.f : 32.f);
    float sqr_r  = (ri == 0) ? 0.70710678f : (ri == 1 ? 1.f : 1.41421356f);
    float sqr_ir = (ri == 0) ? 1.41421356f : (ri == 1 ? 1.f : 0.70710678f);
    float hh = 16.f * sv * sqr_r;
    float ww = 16.f * sv * sqr_ir;
    float acy = 16.f * (float)(y + 1) - 25.f;
    float acx = 16.f * (float)(x + 1) - 25.f;
    float ay1 = acy - 0.5f * hh, ay2 = acy + 0.5f * hh;
    float ax1 = acx - 0.5f * ww, ax2 = acx + 0.5f * ww;
    float ah = ay2 - ay1, aw = ax2 - ax1;
    float cy0 = ay1 + 0.5f * ah, cx0 = ax1 + 0.5f * aw;
    float cy = d0 * ah + cy0, cx = d1 * aw + cx0;
    float bh = expf(d2) * ah, bw = expf(d3) * aw;
    float y1 = cy - 0.5f * bh, x1 = cx - 0.5f * bw;
    float y2 = cy + 0.5f * bh, x2 = cx + 0.5f * bw;
    y1 = fminf(fmaxf(y1, 0.f), 800.f); y2 = fminf(fmaxf(y2, 0.f), 800.f);
    x1 = fminf(fmaxf(x1, 0.f), 800.f); x2 = fminf(fmaxf(x2, 0.f), 800.f);
    bool ok = ((y2 - y1) >= 16.f) && ((x2 - x1) >= 16.f);
    int gi = b * 22500 + n * 9 + a;
    ((float4*)boxes)[gi] = make_float4(y1, x1, y2, x2);
    scores[gi] = (ok && fg == fg) ? fg : NEGV;
  }
}

// ------------------------------------------------------------------
// Top-6000 radix select (verbatim, verified)
// ------------------------------------------------------------------
__global__ __launch_bounds__(1024) void topk_kernel(
    const float* __restrict__ scores, const float* __restrict__ boxes,
    float* __restrict__ tsc, float* __restrict__ tbx, int* __restrict__ tidx) {
  const int b = blockIdx.x, tid = threadIdx.x;
  __shared__ unsigned hist[256];
  __shared__ unsigned long long sh_pref;
  __shared__ unsigned sh_rem, sh_cnt;
  const float* sc = scores + b * 22500;
  if (tid == 0) { sh_pref = 0ull; sh_rem = 6000u; }
  __syncthreads();
  for (int pass = 0; pass < 6; ++pass) {
    const int shift = 40 - pass * 8;
    if (tid < 256) hist[tid] = 0u;
    __syncthreads();
    const unsigned long long pref = sh_pref;
    for (int j = tid; j < 22500; j += 1024) {
      unsigned long long key = key48(sc[j], j);
      if ((key >> (shift + 8)) == pref)
        atomicAdd(&hist[(unsigned)(key >> shift) & 255u], 1u);
    }
    __syncthreads();
    if (tid == 0) {
      unsigned rem = sh_rem;
      unsigned c = 0; int sel = 0;
      for (int bin = 255; bin >= 0; --bin) {
        unsigned nc = c + hist[bin];
        if (nc >= rem) { sel = bin; break; }
        c = nc;
      }
      sh_rem = rem - c;
      sh_pref = (sh_pref << 8) | (unsigned long long)sel;
    }
    __syncthreads();
  }
  const unsigned long long T = sh_pref;
  if (tid == 0) sh_cnt = 0u;
  __syncthreads();
  const float4* bx4 = (const float4*)boxes;
  float4* tb4 = (float4*)tbx;
  for (int j = tid; j < 22500; j += 1024) {
    unsigned long long key = key48(sc[j], j);
    if (key >= T) {
      unsigned slot = atomicAdd(&sh_cnt, 1u);
      if (slot < 6000u) {
        tsc[b * 6000 + slot] = sc[j];
        tidx[b * 6000 + slot] = j;
        tb4[b * 6000 + slot] = bx4[b * 22500 + j];
      }
    }
  }
}

// ------------------------------------------------------------------
// Rank-sort (verbatim, verified)
// ------------------------------------------------------------------
__global__ __launch_bounds__(256) void rank_kernel(
    const float* __restrict__ tsc, const int* __restrict__ tidx,
    const float* __restrict__ tbx,
    float* __restrict__ sbx, float* __restrict__ ssc) {
  const int b = blockIdx.y;
  const int c = blockIdx.x * 256 + threadIdx.x;
  const int lane = threadIdx.x & 63;
  const float* scb = tsc + b * 6000;
  const int* idb = tidx + b * 6000;
  unsigned long long kc = (c < 6000) ? key48(scb[c], idb[c]) : 0ull;
  int rank = 0;
  for (int t = 0; t < 94; ++t) {
    int j = t * 64 + lane;
    unsigned long long kj = (j < 6000) ? key48(scb[j], idb[j]) : 0ull;
    #pragma unroll
    for (int r = 0; r < 64; ++r) {
      unsigned long long kk = __shfl(kj, r);
      rank += (kk > kc) ? 1 : 0;
    }
  }
  if (c < 6000) {
    ((float4*)sbx)[b * 6000 + rank] = ((const float4*)tbx)[b * 6000 + c];
    ssc[b * 6000 + rank] = scb[c];
  }
}

// ------------------------------------------------------------------
// Suppression bitmask (verbatim, verified)
// ------------------------------------------------------------------
__global__ __launch_bounds__(256) void mask_kernel(
    const float* __restrict__ sbx, unsigned long long* __restrict__ mask) {
  const int b = blockIdx.y;
  const int row = blockIdx.x * 64 + (threadIdx.x & 63);
  const int wseg = threadIdx.x >> 6;
  __shared__ float4 jb[512];
  const float4* sb4 = (const float4*)sbx + (size_t)b * 6000;
  float4 rb = sb4[row < 6000 ? row : 5999];
  const float ra = (rb.z - rb.x) * (rb.w - rb.y);
  unsigned long long m[24];
  #pragma unroll
  for (int q = 0; q < 24; ++q) m[q] = 0ull;
  for (int jt = 0; jt < 12; ++jt) {
    __syncthreads();
    for (int s = threadIdx.x; s < 512; s += 256) {
      int j = jt * 512 + s;
      jb[s] = (j < 6000) ? sb4[j] : make_float4(0.f, 0.f, 0.f, 0.f);
    }
    __syncthreads();
    #pragma unroll
    for (int ww = 0; ww < 2; ++ww) {
      int w = jt * 8 + wseg * 2 + ww;
      if (w >= 94) continue;
      int j0 = (wseg * 2 + ww) * 64;
      unsigned long long bits = 0ull;
      #pragma unroll
      for (int u = 0; u < 64; ++u) {
        float4 bb = jb[j0 + u];
        float aj = (bb.z - bb.x) * (bb.w - bb.y);
        float yy1 = fmaxf(rb.x, bb.x), xx1 = fmaxf(rb.y, bb.y);
        float yy2 = fminf(rb.z, bb.z), xx2 = fminf(rb.w, bb.w);
        float inter = fmaxf(yy2 - yy1, 0.f) * fmaxf(xx2 - xx1, 0.f);
        float iou = inter / (((ra + aj) - inter) + 1e-9f);
        bits |= (iou > 0.7f) ? (1ull << u) : 0ull;
      }
      m[jt * 2 + ww] = bits;
    }
  }
  if (row < 6000) {
    unsigned long long* mr = mask + (size_t)(b * 6000 + row) * 94;
    #pragma unroll
    for (int jt = 0; jt < 12; ++jt)
      #pragma unroll
      for (int ww = 0; ww < 2; ++ww) {
        int w = jt * 8 + wseg * 2 + ww;
        if (w < 94) mr[w] = m[jt * 2 + ww];
      }
  }
}

// ------------------------------------------------------------------
// Greedy bitmask walk, chunked (verbatim r12/r13, verified)
// ------------------------------------------------------------------
__global__ __launch_bounds__(64) void nmsbit_kernel(
    const float* __restrict__ ssc, const float* __restrict__ sbx,
    const unsigned long long* __restrict__ mask, float* __restrict__ out) {
  const int b = blockIdx.x, lane = threadIdx.x;
  __shared__ unsigned long long live[94];
  __shared__ int picks[300];
  int cnt = 0;
  for (int j = lane; j < 6000; j += 64)
    cnt += (ssc[b * 6000 + j] > NEGH) ? 1 : 0;
  #pragma unroll
  for (int off = 32; off > 0; off >>= 1) cnt += __shfl_down(cnt, off);
  const int nvalid = __shfl(cnt, 0);
  for (int w = lane; w < 94; w += 64) {
    int base = w * 64;
    unsigned long long mm;
    if (base + 64 <= nvalid) mm = ~0ull;
    else if (base >= nvalid) mm = 0ull;
    else mm = (~0ull) >> (64 - (nvalid - base));
    live[w] = mm;
  }
  __syncthreads();

  int np = 0;
  for (int c = 0; c < 94 && np < 300; ++c) {
    unsigned long long bits = live[c];
    if (bits == 0ull) continue;
    int row = c * 64 + lane;
    unsigned long long dw = (row < 6000)
        ? mask[(size_t)(b * 6000 + row) * 94 + c] : 0ull;
    unsigned long long prows = 0ull;
    while (bits != 0ull && np < 300) {
      int bpos = __ffsll(bits) - 1;
      if (lane == 0) picks[np] = c * 64 + bpos;
      np++;
      prows |= (1ull << bpos);
      unsigned long long dwb = __shfl(dw, bpos);
      bits &= ~dwb;
      bits &= ~(1ull << bpos);
    }
    unsigned long long acc0 = 0ull, acc1 = 0ull;
    unsigned long long pr = prows;
    while (pr != 0ull) {
      int bpos = __ffsll(pr) - 1; pr &= pr - 1ull;
      const unsigned long long* mr = mask + (size_t)(b * 6000 + c * 64 + bpos) * 94;
      acc0 |= mr[lane];
      if (lane < 30) acc1 |= mr[lane + 64];
    }
    if (prows != 0ull) {
      live[lane] &= ~acc0;
      if (lane < 30) live[lane + 64] &= ~acc1;
      __syncthreads();
    }
  }
  __syncthreads();

  float* rois = out;
  float* rsc  = out + 12000;
  for (int t = lane; t < 300; t += 64) {
    float* rp = rois + (size_t)(b * 300 + t) * 5;
    if (t < np) {
      int i = picks[t];
      float4 bb = ((const float4*)sbx)[b * 6000 + i];
      rp[0] = (float)b; rp[1] = bb.x; rp[2] = bb.y; rp[3] = bb.z; rp[4] = bb.w;
      rsc[b * 300 + t] = ssc[b * 6000 + i];
    } else {
      rp[0] = 0.f; rp[1] = 0.f; rp[2] = 0.f; rp[3] = 0.f; rp[4] = 0.f;
      rsc[b * 300 + t] = 0.f;
    }
  }
}

// ------------------------------------------------------------------
extern "C" void kernel_launch(void* const* d_in, const int* in_sizes, int n_in,
                              void* d_out, int out_size, void* d_ws, size_t ws_size,
                              hipStream_t stream) {
  const float* feat = (const float*)d_in[0];
  const float* W1   = (const float*)d_in[1];
  const float* b1   = (const float*)d_in[2];
  const float* Wreg = (const float*)d_in[3];
  const float* breg = (const float*)d_in[4];
  const float* Wcls = (const float*)d_in[5];
  const float* bcls = (const float*)d_in[6];
  float* out = (float*)d_out;
  float* ws  = (float*)d_ws;

  // ws layout unchanged from r13 (W1f uses 2,359,296 of the 3,538,944-f
  // W1pack region). NEED = 59,978,368 B (proven available).
  const size_t NEED = 59978368ull;
  if (ws_size >= NEED) {
    float* W1f    = ws;
    float* conv1  = ws + 3538944;
    unsigned long long* mask = (unsigned long long*)(ws + 3538944);
    float* boxes  = ws + 13778944;
    float* sbx    = ws + 13778944;
    float* ssc    = ws + 13970944;
    float* scores = ws + 14498944;
    float* tbx    = ws + 14678944;
    float* tsc    = ws + 14870944;
    int*   tidx   = (int*)(ws + 14918944);
    float* Wt     = ws + 14966944;

    w1pack_kernel<<<512, 256, 0, stream>>>(W1, W1f);
    wtpack_kernel<<<108, 256, 0, stream>>>(Wreg, Wcls, Wt);
    conv_mfma_kernel<<<640, 256, 0, stream>>>(feat, W1f, b1, conv1);
    heads_kernel<<<1250, 256, 0, stream>>>(conv1, Wt, breg, bcls, boxes, scores);
    topk_kernel<<<8, 1024, 0, stream>>>(scores, boxes, tsc, tbx, tidx);
    rank_kernel<<<dim3(24, 8), 256, 0, stream>>>(tsc, tidx, tbx, sbx, ssc);
    mask_kernel<<<dim3(94, 8), 256, 0, stream>>>(sbx, mask);
    nmsbit_kernel<<<8, 64, 0, stream>>>(ssc, sbx, mask, out);
  }
}

// Round 15
// 1480.526 us; speedup vs baseline: 1.0499x; 1.0499x over previous
//
#include <hip/hip_runtime.h>
#include <hip/hip_bf16.h>
#include <math.h>

#define NEGV -1e9f
#define NEGH -5e8f

typedef __attribute__((ext_vector_type(8))) short short8;
typedef __attribute__((ext_vector_type(4))) float f32x4;

__device__ __forceinline__ unsigned fkey(float f) {
  unsigned u = __float_as_uint(f);
  return (u & 0x80000000u) ? ~u : (u | 0x80000000u);
}
__device__ __forceinline__ unsigned long long key48(float s, int j) {
  return ((unsigned long long)fkey(s) << 15) | (unsigned long long)(32767 - j);
}
__device__ __forceinline__ unsigned short bf16_rne(float v) {
  unsigned u = __float_as_uint(v);
  unsigned r = u + 0x7FFFu + ((u >> 16) & 1u);
  return (unsigned short)(r >> 16);
}
__device__ __forceinline__ float bf16_f(unsigned short h) {
  return __uint_as_float(((unsigned)h) << 16);
}

#if defined(__has_builtin)
#if __has_builtin(__builtin_amdgcn_global_load_lds)
#define HAS_GLL 1
#endif
#endif

__device__ __forceinline__ void stage16(const char* gsrc_lane, char* ldsbase, int ln) {
#ifdef HAS_GLL
  typedef unsigned int __attribute__((address_space(1))) gu32;
  typedef unsigned int __attribute__((address_space(3))) lu32;
  __builtin_amdgcn_global_load_lds((const gu32*)gsrc_lane, (lu32*)ldsbase, 16, 0, 0);
#else
  *(uint4*)(ldsbase + ln * 16) = *(const uint4*)gsrc_lane;
#endif
}

// ==================================================================
// Packed-tile byte layout (per plane: rowpairs x 128B):
//   byte(row,k) = (row>>1)*128 + ((((row&1)<<6) + 2k) ^ (((row>>1)&7)<<4))
// W1pack image order: [ct=4][s=144][plane hi/mid/lo][2048 dw]
// K-order: TAP-MAJOR — FROZEN (r11: accumulation-order changes cascade
// through NMS ties into absmax 800). conv1 bitwise = r5-r13 lineage.
// ==================================================================

// ------------------------------------------------------------------
// Pack W1 (coalesced, verbatim r12/r13 — bytes verified identical).
// ------------------------------------------------------------------
__global__ __launch_bounds__(256) void w1pack_kernel(
    const float* __restrict__ W1, unsigned* __restrict__ W1pack) {
  int g = blockIdx.x * 256 + threadIdx.x;   // 512*256 = 131072 exact
  int oc = g >> 8;
  int cp = g & 255;
  int cin = cp * 2;
  int ct = oc >> 7;
  int row = oc & 127;
  float buf[18];
  const float* src = W1 + (size_t)oc * 4608 + cin * 9;
  #pragma unroll
  for (int i = 0; i < 18; ++i) buf[i] = src[i];
  int k = cin & 31;
  int R = row >> 1;
  int val = ((row & 1) << 6) | (k << 1);
  int tb = (R << 7) | (val ^ ((R & 7) << 4));
  int dwimg = tb >> 2;
  int sBase = cp >> 4;                      // cin>>5
  #pragma unroll
  for (int tap = 0; tap < 9; ++tap) {
    float w0 = buf[tap], w1 = buf[9 + tap];
    unsigned short h0 = bf16_rne(w0), h1 = bf16_rne(w1);
    float r0 = w0 - bf16_f(h0), r1 = w1 - bf16_f(h1);
    unsigned short m0 = bf16_rne(r0), m1 = bf16_rne(r1);
    unsigned short l0 = bf16_rne(r0 - bf16_f(m0)), l1 = bf16_rne(r1 - bf16_f(m1));
    int s = tap * 16 + sBase;               // tap-major (frozen)
    size_t base = ((size_t)(ct * 144 + s) * 3) * 2048 + dwimg;
    W1pack[base]        = (unsigned)h0 | ((unsigned)h1 << 16);
    W1pack[base + 2048] = (unsigned)m0 | ((unsigned)m1 << 16);
    W1pack[base + 4096] = (unsigned)l0 | ((unsigned)l1 << 16);
  }
}

// ------------------------------------------------------------------
// Heads weight transpose (verbatim r13, verified)
// ------------------------------------------------------------------
__global__ __launch_bounds__(256) void wtpack_kernel(
    const float* __restrict__ Wreg, const float* __restrict__ Wcls,
    float* __restrict__ Wt) {
  int i = blockIdx.x * 256 + threadIdx.x;   // 108*256 = 27648 exact
  int c = i / 54, j = i - c * 54;
  Wt[i] = (j < 36) ? Wreg[j * 512 + c] : Wcls[(j - 36) * 512 + c];
}

// ------------------------------------------------------------------
// Conv 3x3 split-3 bf16 MFMA GEMM — verbatim BEST-MEASURED text
// (round-7 bench: 770-786 us; dim3 grid, 48KB single-buffer, GLL).
// ------------------------------------------------------------------
__global__ __launch_bounds__(256) void conv_mfma_kernel(
    const float* __restrict__ feat, const char* __restrict__ W1pack,
    const float* __restrict__ b1, float* __restrict__ conv1) {
  __shared__ char smem[49152];
  const int tid = threadIdx.x;
  const int b  = blockIdx.z;
  const int ct = blockIdx.y;
  const int n0 = blockIdx.x * 128;
  const int wv = tid >> 6, ln = tid & 63;

  const int spix = tid & 127;
  const int kh   = tid >> 7;
  int p = n0 + spix; if (p > 2499) p = 2499;
  const int pyy = p / 50;
  const int pxx = p - pyy * 50;
  const float* featb = feat + (size_t)b * 512 * 2500;
  const char* wsrc = W1pack + (size_t)ct * 144 * 24576;

  const int wch0  = (wv >> 1) * 64;
  const int wpix0 = (wv & 1) * 64;
  const int lrow = ln & 15, lg = ln >> 4;

  f32x4 acc[4][4];
  #pragma unroll
  for (int i = 0; i < 4; ++i)
    #pragma unroll
    for (int j = 0; j < 4; ++j) acc[i][j] = (f32x4)0.f;

  float u[16];

  auto loadFeat = [&](int s) {
    int tap = s >> 4;
    int dy = tap / 3, dx = tap - dy * 3;
    int iy = pyy + dy - 1, ix = pxx + dx - 1;
    bool ok = ((unsigned)iy < 50u) && ((unsigned)ix < 50u);
    int cinb = ((s & 15) << 5) + kh * 16;
    const float* base = featb + (size_t)cinb * 2500 + iy * 50 + ix;
    #pragma unroll
    for (int i = 0; i < 16; ++i) u[i] = ok ? base[(size_t)i * 2500] : 0.f;
  };
  auto issueA = [&](int s) {
    const char* src = wsrc + (size_t)s * 24576;
    char* lbase = smem + (tid >> 6) * 1024;
    #pragma unroll
    for (int c = 0; c < 6; ++c)
      stage16(src + c * 4096 + tid * 16, lbase + c * 4096, ln);
  };
  auto writeB = [&]() {
    unsigned short h[16], m[16], l[16];
    #pragma unroll
    for (int i = 0; i < 16; ++i) {
      float v = u[i];
      h[i] = bf16_rne(v);
      float r1 = v - bf16_f(h[i]);
      m[i] = bf16_rne(r1);
      float r2 = r1 - bf16_f(m[i]);
      l[i] = bf16_rne(r2);
    }
    const int r = spix >> 1;
    const int swz = (r & 7) << 4;
    char* rowb = smem + 24576 + r * 128;
    #pragma unroll
    for (int pl = 0; pl < 3; ++pl) {
      const unsigned short* sp = (pl == 0) ? h : (pl == 1 ? m : l);
      char* pb = rowb + pl * 8192;
      #pragma unroll
      for (int q = 0; q < 4; ++q) {
        int pre = ((spix & 1) << 6) + kh * 32 + q * 8;
        uint2 w;
        w.x = (unsigned)sp[q*4]   | ((unsigned)sp[q*4+1] << 16);
        w.y = (unsigned)sp[q*4+2] | ((unsigned)sp[q*4+3] << 16);
        *(uint2*)(pb + (pre ^ swz)) = w;
      }
    }
  };
  auto rdFrag = [&](const char* base, int row) -> short8 {
    int byte = (row >> 1) * 128 +
               ((((row & 1) << 6) + (lg << 4)) ^ (((row >> 1) & 7) << 4));
    return *(const short8*)(base + byte);
  };

  loadFeat(0);
  #pragma unroll 1
  for (int s = 0; s < 144; ++s) {
    __syncthreads();
    issueA(s);
    writeB();
    __syncthreads();
    if (s + 1 < 144) loadFeat(s + 1);
    short8 fa[3][4];
    #pragma unroll
    for (int pl = 0; pl < 3; ++pl)
      #pragma unroll
      for (int f = 0; f < 4; ++f)
        fa[pl][f] = rdFrag(smem + pl * 8192, wch0 + f * 16 + lrow);
    #pragma unroll
    for (int jb = 0; jb < 3; ++jb) {
      short8 fb[4];
      #pragma unroll
      for (int f = 0; f < 4; ++f)
        fb[f] = rdFrag(smem + 24576 + jb * 8192, wpix0 + f * 16 + lrow);
      const int na = 3 - jb;
      #pragma unroll
      for (int ap = 0; ap < 3; ++ap) {
        if (ap < na) {
          #pragma unroll
          for (int i = 0; i < 4; ++i)
            #pragma unroll
            for (int j = 0; j < 4; ++j)
              acc[i][j] = __builtin_amdgcn_mfma_f32_16x16x32_bf16(
                  fa[ap][i], fb[j], acc[i][j], 0, 0, 0);
        }
      }
    }
  }

  const int chb = ct * 128 + wch0 + lg * 4;
  #pragma unroll
  for (int i = 0; i < 4; ++i) {
    int ch = chb + i * 16;
    float4 bias = *(const float4*)&b1[ch];
    #pragma unroll
    for (int j = 0; j < 4; ++j) {
      int pix = n0 + wpix0 + j * 16 + lrow;
      if (pix < 2500) {
        float4 o;
        o.x = fmaxf(acc[i][j][0] + bias.x, 0.f);
        o.y = fmaxf(acc[i][j][1] + bias.y, 0.f);
        o.z = fmaxf(acc[i][j][2] + bias.z, 0.f);
        o.w = fmaxf(acc[i][j][3] + bias.w, 0.f);
        *(float4*)&conv1[(size_t)(b * 2500 + pix) * 512 + ch] = o;
      }
    }
  }
}

// ------------------------------------------------------------------
// Heads v2 (verbatim r13, verified)
// ------------------------------------------------------------------
__global__ __launch_bounds__(256) void heads_kernel(
    const float* __restrict__ conv1, const float* __restrict__ Wt,
    const float* __restrict__ breg, const float* __restrict__ bcls,
    float* __restrict__ boxes, float* __restrict__ scores) {
  __shared__ float v[16][512];
  __shared__ float o54[16][56];
  const int tid = threadIdx.x;
  const int wvi = tid >> 6, lane = tid & 63;
  const int pix0 = blockIdx.x * 16;
  float4* vf = (float4*)v;
  const float4* src4 = (const float4*)(conv1 + (size_t)pix0 * 512);
  #pragma unroll
  for (int i = 0; i < 8; ++i) vf[i * 256 + tid] = src4[i * 256 + tid];
  __syncthreads();

  if (lane < 54) {
    float s[4][4];
    #pragma unroll
    for (int p = 0; p < 4; ++p)
      #pragma unroll
      for (int q = 0; q < 4; ++q) s[p][q] = 0.f;
    const int pl0 = wvi * 4;
    for (int c = 0; c < 512; c += 4) {
      float w0 = Wt[(c + 0) * 54 + lane];
      float w1 = Wt[(c + 1) * 54 + lane];
      float w2 = Wt[(c + 2) * 54 + lane];
      float w3 = Wt[(c + 3) * 54 + lane];
      #pragma unroll
      for (int p = 0; p < 4; ++p) {
        s[p][0] = fmaf(v[pl0 + p][c],     w0, s[p][0]);
        s[p][1] = fmaf(v[pl0 + p][c + 1], w1, s[p][1]);
        s[p][2] = fmaf(v[pl0 + p][c + 2], w2, s[p][2]);
        s[p][3] = fmaf(v[pl0 + p][c + 3], w3, s[p][3]);
      }
    }
    float bias = (lane < 36) ? breg[lane] : bcls[lane - 36];
    #pragma unroll
    for (int p = 0; p < 4; ++p)
      o54[pl0 + p][lane] = (s[p][0] + s[p][1]) + (s[p][2] + s[p][3]) + bias;
  }
  __syncthreads();

  if (tid < 144) {
    const int pl = tid / 9;
    const int a  = tid - pl * 9;
    const int pix = pix0 + pl;
    const int b = pix / 2500;
    const int n = pix - b * 2500;
    const int y = n / 50, x = n - y * 50;
    float d0 = o54[pl][a * 4 + 0], d1 = o54[pl][a * 4 + 1];
    float d2 = o54[pl][a * 4 + 2], d3 = o54[pl][a * 4 + 3];
    float sc0 = o54[pl][36 + a * 2], sc1 = o54[pl][36 + a * 2 + 1];
    float mx = fmaxf(sc0, sc1);
    float e0 = expf(sc0 - mx), e1 = expf(sc1 - mx);
    float fg = e1 / (e0 + e1);
    const int ri = a / 3;
    const int si = a - ri * 3;
    float sv = (si == 0) ? 8.f : (si == 1 ? 16.f : 32.f);
    float sqr_r  = (ri == 0) ? 0.70710678f : (ri == 1 ? 1.f : 1.41421356f);
    float sqr_ir = (ri == 0) ? 1.41421356f : (ri == 1 ? 1.f : 0.70710678f);
    float hh = 16.f * sv * sqr_r;
    float ww = 16.f * sv * sqr_ir;
    float acy = 16.f * (float)(y + 1) - 25.f;
    float acx = 16.f * (float)(x + 1) - 25.f;
    float ay1 = acy - 0.5f * hh, ay2 = acy + 0.5f * hh;
    float ax1 = acx - 0.5f * ww, ax2 = acx + 0.5f * ww;
    float ah = ay2 - ay1, aw = ax2 - ax1;
    float cy0 = ay1 + 0.5f * ah, cx0 = ax1 + 0.5f * aw;
    float cy = d0 * ah + cy0, cx = d1 * aw + cx0;
    float bh = expf(d2) * ah, bw = expf(d3) * aw;
    float y1 = cy - 0.5f * bh, x1 = cx - 0.5f * bw;
    float y2 = cy + 0.5f * bh, x2 = cx + 0.5f * bw;
    y1 = fminf(fmaxf(y1, 0.f), 800.f); y2 = fminf(fmaxf(y2, 0.f), 800.f);
    x1 = fminf(fmaxf(x1, 0.f), 800.f); x2 = fminf(fmaxf(x2, 0.f), 800.f);
    bool ok = ((y2 - y1) >= 16.f) && ((x2 - x1) >= 16.f);
    int gi = b * 22500 + n * 9 + a;
    ((float4*)boxes)[gi] = make_float4(y1, x1, y2, x2);
    scores[gi] = (ok && fg == fg) ? fg : NEGV;
  }
}

// ------------------------------------------------------------------
// Top-6000 radix select — per-wave histograms (16x less LDS-atomic
// contention); count arithmetic identical -> same selected set.
// ------------------------------------------------------------------
__global__ __launch_bounds__(1024) void topk_kernel(
    const float* __restrict__ scores, const float* __restrict__ boxes,
    float* __restrict__ tsc, float* __restrict__ tbx, int* __restrict__ tidx) {
  const int b = blockIdx.x, tid = threadIdx.x;
  __shared__ unsigned hist[16][256];
  __shared__ unsigned long long sh_pref;
  __shared__ unsigned sh_rem, sh_cnt;
  const int wid = tid >> 6;
  const float* sc = scores + b * 22500;
  if (tid == 0) { sh_pref = 0ull; sh_rem = 6000u; }
  __syncthreads();
  for (int pass = 0; pass < 6; ++pass) {
    const int shift = 40 - pass * 8;
    #pragma unroll
    for (int i = tid; i < 4096; i += 1024) ((unsigned*)hist)[i] = 0u;
    __syncthreads();
    const unsigned long long pref = sh_pref;
    for (int j = tid; j < 22500; j += 1024) {
      unsigned long long key = key48(sc[j], j);
      if ((key >> (shift + 8)) == pref)
        atomicAdd(&hist[wid][(unsigned)(key >> shift) & 255u], 1u);
    }
    __syncthreads();
    if (tid < 256) {
      unsigned s = 0;
      #pragma unroll
      for (int w = 0; w < 16; ++w) s += hist[w][tid];
      hist[0][tid] = s;
    }
    __syncthreads();
    if (tid == 0) {
      unsigned rem = sh_rem;
      unsigned c = 0; int sel = 0;
      for (int bin = 255; bin >= 0; --bin) {
        unsigned nc = c + hist[0][bin];
        if (nc >= rem) { sel = bin; break; }
        c = nc;
      }
      sh_rem = rem - c;
      sh_pref = (sh_pref << 8) | (unsigned long long)sel;
    }
    __syncthreads();
  }
  const unsigned long long T = sh_pref;
  if (tid == 0) sh_cnt = 0u;
  __syncthreads();
  const float4* bx4 = (const float4*)boxes;
  float4* tb4 = (float4*)tbx;
  for (int j = tid; j < 22500; j += 1024) {
    unsigned long long key = key48(sc[j], j);
    if (key >= T) {
      unsigned slot = atomicAdd(&sh_cnt, 1u);
      if (slot < 6000u) {
        tsc[b * 6000 + slot] = sc[j];
        tidx[b * 6000 + slot] = j;
        tb4[b * 6000 + slot] = bx4[b * 22500 + j];
      }
    }
  }
}

// ------------------------------------------------------------------
// Rank-sort (verbatim, verified)
// ------------------------------------------------------------------
__global__ __launch_bounds__(256) void rank_kernel(
    const float* __restrict__ tsc, const int* __restrict__ tidx,
    const float* __restrict__ tbx,
    float* __restrict__ sbx, float* __restrict__ ssc) {
  const int b = blockIdx.y;
  const int c = blockIdx.x * 256 + threadIdx.x;
  const int lane = threadIdx.x & 63;
  const float* scb = tsc + b * 6000;
  const int* idb = tidx + b * 6000;
  unsigned long long kc = (c < 6000) ? key48(scb[c], idb[c]) : 0ull;
  int rank = 0;
  for (int t = 0; t < 94; ++t) {
    int j = t * 64 + lane;
    unsigned long long kj = (j < 6000) ? key48(scb[j], idb[j]) : 0ull;
    #pragma unroll
    for (int r = 0; r < 64; ++r) {
      unsigned long long kk = __shfl(kj, r);
      rank += (kk > kc) ? 1 : 0;
    }
  }
  if (c < 6000) {
    ((float4*)sbx)[b * 6000 + rank] = ((const float4*)tbx)[b * 6000 + c];
    ssc[b * 6000 + rank] = scb[c];
  }
}

// ------------------------------------------------------------------
// Suppression bitmask (verbatim, verified)
// ------------------------------------------------------------------
__global__ __launch_bounds__(256) void mask_kernel(
    const float* __restrict__ sbx, unsigned long long* __restrict__ mask) {
  const int b = blockIdx.y;
  const int row = blockIdx.x * 64 + (threadIdx.x & 63);
  const int wseg = threadIdx.x >> 6;
  __shared__ float4 jb[512];
  const float4* sb4 = (const float4*)sbx + (size_t)b * 6000;
  float4 rb = sb4[row < 6000 ? row : 5999];
  const float ra = (rb.z - rb.x) * (rb.w - rb.y);
  unsigned long long m[24];
  #pragma unroll
  for (int q = 0; q < 24; ++q) m[q] = 0ull;
  for (int jt = 0; jt < 12; ++jt) {
    __syncthreads();
    for (int s = threadIdx.x; s < 512; s += 256) {
      int j = jt * 512 + s;
      jb[s] = (j < 6000) ? sb4[j] : make_float4(0.f, 0.f, 0.f, 0.f);
    }
    __syncthreads();
    #pragma unroll
    for (int ww = 0; ww < 2; ++ww) {
      int w = jt * 8 + wseg * 2 + ww;
      if (w >= 94) continue;
      int j0 = (wseg * 2 + ww) * 64;
      unsigned long long bits = 0ull;
      #pragma unroll
      for (int u = 0; u < 64; ++u) {
        float4 bb = jb[j0 + u];
        float aj = (bb.z - bb.x) * (bb.w - bb.y);
        float yy1 = fmaxf(rb.x, bb.x), xx1 = fmaxf(rb.y, bb.y);
        float yy2 = fminf(rb.z, bb.z), xx2 = fminf(rb.w, bb.w);
        float inter = fmaxf(yy2 - yy1, 0.f) * fmaxf(xx2 - xx1, 0.f);
        float iou = inter / (((ra + aj) - inter) + 1e-9f);
        bits |= (iou > 0.7f) ? (1ull << u) : 0ull;
      }
      m[jt * 2 + ww] = bits;
    }
  }
  if (row < 6000) {
    unsigned long long* mr = mask + (size_t)(b * 6000 + row) * 94;
    #pragma unroll
    for (int jt = 0; jt < 12; ++jt)
      #pragma unroll
      for (int ww = 0; ww < 2; ++ww) {
        int w = jt * 8 + wseg * 2 + ww;
        if (w < 94) mr[w] = m[jt * 2 + ww];
      }
  }
}

// ------------------------------------------------------------------
// Greedy bitmask walk, chunked + 4-wide ILP apply (OR is
// order-independent -> identical result to r12/r13).
// ------------------------------------------------------------------
__global__ __launch_bounds__(64) void nmsbit_kernel(
    const float* __restrict__ ssc, const float* __restrict__ sbx,
    const unsigned long long* __restrict__ mask, float* __restrict__ out) {
  const int b = blockIdx.x, lane = threadIdx.x;
  __shared__ unsigned long long live[94];
  __shared__ int picks[300];
  const unsigned long long* mbase = mask + (size_t)b * 6000 * 94;
  int cnt = 0;
  for (int j = lane; j < 6000; j += 64)
    cnt += (ssc[b * 6000 + j] > NEGH) ? 1 : 0;
  #pragma unroll
  for (int off = 32; off > 0; off >>= 1) cnt += __shfl_down(cnt, off);
  const int nvalid = __shfl(cnt, 0);
  for (int w = lane; w < 94; w += 64) {
    int base = w * 64;
    unsigned long long mm;
    if (base + 64 <= nvalid) mm = ~0ull;
    else if (base >= nvalid) mm = 0ull;
    else mm = (~0ull) >> (64 - (nvalid - base));
    live[w] = mm;
  }
  __syncthreads();

  int np = 0;
  for (int c = 0; c < 94 && np < 300; ++c) {
    unsigned long long bits = live[c];
    if (bits == 0ull) continue;
    int row = c * 64 + lane;
    unsigned long long dw = (row < 6000) ? mbase[(size_t)row * 94 + c] : 0ull;
    unsigned long long prows = 0ull;
    while (bits != 0ull && np < 300) {
      int bpos = __ffsll(bits) - 1;
      if (lane == 0) picks[np] = c * 64 + bpos;
      np++;
      prows |= (1ull << bpos);
      unsigned long long dwb = __shfl(dw, bpos);
      bits &= ~dwb;
      bits &= ~(1ull << bpos);
    }
    unsigned long long acc0 = 0ull, acc1 = 0ull;
    unsigned long long pr = prows;
    while (pr != 0ull) {
      int r0, r1 = -1, r2 = -1, r3 = -1;
      r0 = __ffsll(pr) - 1; pr &= pr - 1ull;
      if (pr) { r1 = __ffsll(pr) - 1; pr &= pr - 1ull; }
      if (r1 >= 0 && pr) { r2 = __ffsll(pr) - 1; pr &= pr - 1ull; }
      if (r2 >= 0 && pr) { r3 = __ffsll(pr) - 1; pr &= pr - 1ull; }
      const unsigned long long* q0 = mbase + (size_t)(c * 64 + r0) * 94;
      unsigned long long a0 = q0[lane];
      unsigned long long a1 = (lane < 30) ? q0[lane + 64] : 0ull;
      unsigned long long b0 = 0ull, b1 = 0ull, c0 = 0ull, c1 = 0ull,
                         d0 = 0ull, d1 = 0ull;
      if (r1 >= 0) {
        const unsigned long long* q = mbase + (size_t)(c * 64 + r1) * 94;
        b0 = q[lane]; b1 = (lane < 30) ? q[lane + 64] : 0ull;
      }
      if (r2 >= 0) {
        const unsigned long long* q = mbase + (size_t)(c * 64 + r2) * 94;
        c0 = q[lane]; c1 = (lane < 30) ? q[lane + 64] : 0ull;
      }
      if (r3 >= 0) {
        const unsigned long long* q = mbase + (size_t)(c * 64 + r3) * 94;
        d0 = q[lane]; d1 = (lane < 30) ? q[lane + 64] : 0ull;
      }
      acc0 |= (a0 | b0) | (c0 | d0);
      acc1 |= (a1 | b1) | (c1 | d1);
    }
    if (prows != 0ull) {
      live[lane] &= ~acc0;
      if (lane < 30) live[lane + 64] &= ~acc1;
      __syncthreads();
    }
  }
  __syncthreads();

  float* rois = out;
  float* rsc  = out + 12000;
  for (int t = lane; t < 300; t += 64) {
    float* rp = rois + (size_t)(b * 300 + t) * 5;
    if (t < np) {
      int i = picks[t];
      float4 bb = ((const float4*)sbx)[b * 6000 + i];
      rp[0] = (float)b; rp[1] = bb.x; rp[2] = bb.y; rp[3] = bb.z; rp[4] = bb.w;
      rsc[b * 300 + t] = ssc[b * 6000 + i];
    } else {
      rp[0] = 0.f; rp[1] = 0.f; rp[2] = 0.f; rp[3] = 0.f; rp[4] = 0.f;
      rsc[b * 300 + t] = 0.f;
    }
  }
}

// ------------------------------------------------------------------
extern "C" void kernel_launch(void* const* d_in, const int* in_sizes, int n_in,
                              void* d_out, int out_size, void* d_ws, size_t ws_size,
                              hipStream_t stream) {
  const float* feat = (const float*)d_in[0];
  const float* W1   = (const float*)d_in[1];
  const float* b1   = (const float*)d_in[2];
  const float* Wreg = (const float*)d_in[3];
  const float* breg = (const float*)d_in[4];
  const float* Wcls = (const float*)d_in[5];
  const float* bcls = (const float*)d_in[6];
  float* out = (float*)d_out;
  float* ws  = (float*)d_ws;

  const size_t NEED = 59978368ull;
  if (ws_size >= NEED) {
    unsigned* W1pack = (unsigned*)ws;
    float* conv1  = ws + 3538944;
    unsigned long long* mask = (unsigned long long*)(ws + 3538944);
    float* boxes  = ws + 13778944;
    float* sbx    = ws + 13778944;
    float* ssc    = ws + 13970944;
    float* scores = ws + 14498944;
    float* tbx    = ws + 14678944;
    float* tsc    = ws + 14870944;
    int*   tidx   = (int*)(ws + 14918944);
    float* Wt     = ws + 14966944;

    w1pack_kernel<<<512, 256, 0, stream>>>(W1, W1pack);
    wtpack_kernel<<<108, 256, 0, stream>>>(Wreg, Wcls, Wt);
    conv_mfma_kernel<<<dim3(20, 4, 8), 256, 0, stream>>>(feat, (const char*)W1pack, b1, conv1);
    heads_kernel<<<1250, 256, 0, stream>>>(conv1, Wt, breg, bcls, boxes, scores);
    topk_kernel<<<8, 1024, 0, stream>>>(scores, boxes, tsc, tbx, tidx);
    rank_kernel<<<dim3(24, 8), 256, 0, stream>>>(tsc, tidx, tbx, sbx, ssc);
    mask_kernel<<<dim3(94, 8), 256, 0, stream>>>(sbx, mask);
    nmsbit_kernel<<<8, 64, 0, stream>>>(ssc, sbx, mask, out);
  }
}

// Round 16
// 1356.530 us; speedup vs baseline: 1.1458x; 1.0914x over previous
//
#include <hip/hip_runtime.h>
#include <hip/hip_bf16.h>
#include <math.h>

#define NEGV -1e9f
#define NEGH -5e8f

typedef __attribute__((ext_vector_type(8))) short short8;
typedef __attribute__((ext_vector_type(4))) float f32x4;

__device__ __forceinline__ unsigned fkey(float f) {
  unsigned u = __float_as_uint(f);
  return (u & 0x80000000u) ? ~u : (u | 0x80000000u);
}
__device__ __forceinline__ unsigned long long key48(float s, int j) {
  return ((unsigned long long)fkey(s) << 15) | (unsigned long long)(32767 - j);
}
__device__ __forceinline__ unsigned short bf16_rne(float v) {
  unsigned u = __float_as_uint(v);
  unsigned r = u + 0x7FFFu + ((u >> 16) & 1u);
  return (unsigned short)(r >> 16);
}
__device__ __forceinline__ float bf16_f(unsigned short h) {
  return __uint_as_float(((unsigned)h) << 16);
}

#if defined(__has_builtin)
#if __has_builtin(__builtin_amdgcn_global_load_lds)
#define HAS_GLL 1
#endif
#endif

__device__ __forceinline__ void stage16(const char* gsrc_lane, char* ldsbase, int ln) {
#ifdef HAS_GLL
  typedef unsigned int __attribute__((address_space(1))) gu32;
  typedef unsigned int __attribute__((address_space(3))) lu32;
  __builtin_amdgcn_global_load_lds((const gu32*)gsrc_lane, (lu32*)ldsbase, 16, 0, 0);
#else
  *(uint4*)(ldsbase + ln * 16) = *(const uint4*)gsrc_lane;
#endif
}

// ==================================================================
// Packed-tile byte layout (per plane: rowpairs x 128B):
//   byte(row,k) = (row>>1)*128 + ((((row&1)<<6) + 2k) ^ (((row>>1)&7)<<4))
// W1pack image order: [ct=4][s=144][plane hi/mid/lo][2048 dw]
// K-order: TAP-MAJOR — FROZEN (r11: accumulation-order changes cascade
// through NMS ties into absmax 800). conv1 bitwise = r5-r15 lineage.
// ==================================================================

// ------------------------------------------------------------------
// Pack W1 (coalesced, verbatim r12-r15 — bytes verified identical).
// ------------------------------------------------------------------
__global__ __launch_bounds__(256) void w1pack_kernel(
    const float* __restrict__ W1, unsigned* __restrict__ W1pack) {
  int g = blockIdx.x * 256 + threadIdx.x;   // 512*256 = 131072 exact
  int oc = g >> 8;
  int cp = g & 255;
  int cin = cp * 2;
  int ct = oc >> 7;
  int row = oc & 127;
  float buf[18];
  const float* src = W1 + (size_t)oc * 4608 + cin * 9;
  #pragma unroll
  for (int i = 0; i < 18; ++i) buf[i] = src[i];
  int k = cin & 31;
  int R = row >> 1;
  int val = ((row & 1) << 6) | (k << 1);
  int tb = (R << 7) | (val ^ ((R & 7) << 4));
  int dwimg = tb >> 2;
  int sBase = cp >> 4;                      // cin>>5
  #pragma unroll
  for (int tap = 0; tap < 9; ++tap) {
    float w0 = buf[tap], w1 = buf[9 + tap];
    unsigned short h0 = bf16_rne(w0), h1 = bf16_rne(w1);
    float r0 = w0 - bf16_f(h0), r1 = w1 - bf16_f(h1);
    unsigned short m0 = bf16_rne(r0), m1 = bf16_rne(r1);
    unsigned short l0 = bf16_rne(r0 - bf16_f(m0)), l1 = bf16_rne(r1 - bf16_f(m1));
    int s = tap * 16 + sBase;               // tap-major (frozen)
    size_t base = ((size_t)(ct * 144 + s) * 3) * 2048 + dwimg;
    W1pack[base]        = (unsigned)h0 | ((unsigned)h1 << 16);
    W1pack[base + 2048] = (unsigned)m0 | ((unsigned)m1 << 16);
    W1pack[base + 4096] = (unsigned)l0 | ((unsigned)l1 << 16);
  }
}

// ------------------------------------------------------------------
// Heads weight transpose v2: group-interleaved for float4 loads:
//   Wt[(c>>2)*216 + j*4 + (c&3)] = W{reg,cls}[j][c]
// Same values, new layout -> heads fp ops unchanged (bitwise-safe).
// ------------------------------------------------------------------
__global__ __launch_bounds__(256) void wtpack_kernel(
    const float* __restrict__ Wreg, const float* __restrict__ Wcls,
    float* __restrict__ Wt) {
  int i = blockIdx.x * 256 + threadIdx.x;   // 108*256 = 27648 exact
  int gg = i / 216;
  int r  = i - gg * 216;
  int j  = r >> 2;
  int c  = gg * 4 + (r & 3);
  Wt[i] = (j < 36) ? Wreg[j * 512 + c] : Wcls[(j - 36) * 512 + c];
}

// ------------------------------------------------------------------
// Conv 3x3 split-3 bf16 MFMA GEMM — verbatim BEST-MEASURED text
// (r7/r15 bench: 756-786 us; dim3 grid, 48KB single-buffer, GLL).
// Structure FROZEN: 7 levers (r8-r14) all null/negative.
// ------------------------------------------------------------------
__global__ __launch_bounds__(256) void conv_mfma_kernel(
    const float* __restrict__ feat, const char* __restrict__ W1pack,
    const float* __restrict__ b1, float* __restrict__ conv1) {
  __shared__ char smem[49152];
  const int tid = threadIdx.x;
  const int b  = blockIdx.z;
  const int ct = blockIdx.y;
  const int n0 = blockIdx.x * 128;
  const int wv = tid >> 6, ln = tid & 63;

  const int spix = tid & 127;
  const int kh   = tid >> 7;
  int p = n0 + spix; if (p > 2499) p = 2499;
  const int pyy = p / 50;
  const int pxx = p - pyy * 50;
  const float* featb = feat + (size_t)b * 512 * 2500;
  const char* wsrc = W1pack + (size_t)ct * 144 * 24576;

  const int wch0  = (wv >> 1) * 64;
  const int wpix0 = (wv & 1) * 64;
  const int lrow = ln & 15, lg = ln >> 4;

  f32x4 acc[4][4];
  #pragma unroll
  for (int i = 0; i < 4; ++i)
    #pragma unroll
    for (int j = 0; j < 4; ++j) acc[i][j] = (f32x4)0.f;

  float u[16];

  auto loadFeat = [&](int s) {
    int tap = s >> 4;
    int dy = tap / 3, dx = tap - dy * 3;
    int iy = pyy + dy - 1, ix = pxx + dx - 1;
    bool ok = ((unsigned)iy < 50u) && ((unsigned)ix < 50u);
    int cinb = ((s & 15) << 5) + kh * 16;
    const float* base = featb + (size_t)cinb * 2500 + iy * 50 + ix;
    #pragma unroll
    for (int i = 0; i < 16; ++i) u[i] = ok ? base[(size_t)i * 2500] : 0.f;
  };
  auto issueA = [&](int s) {
    const char* src = wsrc + (size_t)s * 24576;
    char* lbase = smem + (tid >> 6) * 1024;
    #pragma unroll
    for (int c = 0; c < 6; ++c)
      stage16(src + c * 4096 + tid * 16, lbase + c * 4096, ln);
  };
  auto writeB = [&]() {
    unsigned short h[16], m[16], l[16];
    #pragma unroll
    for (int i = 0; i < 16; ++i) {
      float v = u[i];
      h[i] = bf16_rne(v);
      float r1 = v - bf16_f(h[i]);
      m[i] = bf16_rne(r1);
      float r2 = r1 - bf16_f(m[i]);
      l[i] = bf16_rne(r2);
    }
    const int r = spix >> 1;
    const int swz = (r & 7) << 4;
    char* rowb = smem + 24576 + r * 128;
    #pragma unroll
    for (int pl = 0; pl < 3; ++pl) {
      const unsigned short* sp = (pl == 0) ? h : (pl == 1 ? m : l);
      char* pb = rowb + pl * 8192;
      #pragma unroll
      for (int q = 0; q < 4; ++q) {
        int pre = ((spix & 1) << 6) + kh * 32 + q * 8;
        uint2 w;
        w.x = (unsigned)sp[q*4]   | ((unsigned)sp[q*4+1] << 16);
        w.y = (unsigned)sp[q*4+2] | ((unsigned)sp[q*4+3] << 16);
        *(uint2*)(pb + (pre ^ swz)) = w;
      }
    }
  };
  auto rdFrag = [&](const char* base, int row) -> short8 {
    int byte = (row >> 1) * 128 +
               ((((row & 1) << 6) + (lg << 4)) ^ (((row >> 1) & 7) << 4));
    return *(const short8*)(base + byte);
  };

  loadFeat(0);
  #pragma unroll 1
  for (int s = 0; s < 144; ++s) {
    __syncthreads();
    issueA(s);
    writeB();
    __syncthreads();
    if (s + 1 < 144) loadFeat(s + 1);
    short8 fa[3][4];
    #pragma unroll
    for (int pl = 0; pl < 3; ++pl)
      #pragma unroll
      for (int f = 0; f < 4; ++f)
        fa[pl][f] = rdFrag(smem + pl * 8192, wch0 + f * 16 + lrow);
    #pragma unroll
    for (int jb = 0; jb < 3; ++jb) {
      short8 fb[4];
      #pragma unroll
      for (int f = 0; f < 4; ++f)
        fb[f] = rdFrag(smem + 24576 + jb * 8192, wpix0 + f * 16 + lrow);
      const int na = 3 - jb;
      #pragma unroll
      for (int ap = 0; ap < 3; ++ap) {
        if (ap < na) {
          #pragma unroll
          for (int i = 0; i < 4; ++i)
            #pragma unroll
            for (int j = 0; j < 4; ++j)
              acc[i][j] = __builtin_amdgcn_mfma_f32_16x16x32_bf16(
                  fa[ap][i], fb[j], acc[i][j], 0, 0, 0);
        }
      }
    }
  }

  const int chb = ct * 128 + wch0 + lg * 4;
  #pragma unroll
  for (int i = 0; i < 4; ++i) {
    int ch = chb + i * 16;
    float4 bias = *(const float4*)&b1[ch];
    #pragma unroll
    for (int j = 0; j < 4; ++j) {
      int pix = n0 + wpix0 + j * 16 + lrow;
      if (pix < 2500) {
        float4 o;
        o.x = fmaxf(acc[i][j][0] + bias.x, 0.f);
        o.y = fmaxf(acc[i][j][1] + bias.y, 0.f);
        o.z = fmaxf(acc[i][j][2] + bias.z, 0.f);
        o.w = fmaxf(acc[i][j][3] + bias.w, 0.f);
        *(float4*)&conv1[(size_t)(b * 2500 + pix) * 512 + ch] = o;
      }
    }
  }
}

// ------------------------------------------------------------------
// Heads v3: same fp ops/order as verified v2; weight loads become one
// coalesced float4 per 4-c group via the interleaved Wt layout.
// ------------------------------------------------------------------
__global__ __launch_bounds__(256) void heads_kernel(
    const float* __restrict__ conv1, const float* __restrict__ Wt,
    const float* __restrict__ breg, const float* __restrict__ bcls,
    float* __restrict__ boxes, float* __restrict__ scores) {
  __shared__ float v[16][512];
  __shared__ float o54[16][56];
  const int tid = threadIdx.x;
  const int wvi = tid >> 6, lane = tid & 63;
  const int pix0 = blockIdx.x * 16;
  float4* vf = (float4*)v;
  const float4* src4 = (const float4*)(conv1 + (size_t)pix0 * 512);
  #pragma unroll
  for (int i = 0; i < 8; ++i) vf[i * 256 + tid] = src4[i * 256 + tid];
  __syncthreads();

  if (lane < 54) {
    float s[4][4];
    #pragma unroll
    for (int p = 0; p < 4; ++p)
      #pragma unroll
      for (int q = 0; q < 4; ++q) s[p][q] = 0.f;
    const int pl0 = wvi * 4;
    for (int c = 0; c < 512; c += 4) {
      float4 w = *(const float4*)&Wt[(c >> 2) * 216 + lane * 4];
      #pragma unroll
      for (int p = 0; p < 4; ++p) {
        s[p][0] = fmaf(v[pl0 + p][c],     w.x, s[p][0]);
        s[p][1] = fmaf(v[pl0 + p][c + 1], w.y, s[p][1]);
        s[p][2] = fmaf(v[pl0 + p][c + 2], w.z, s[p][2]);
        s[p][3] = fmaf(v[pl0 + p][c + 3], w.w, s[p][3]);
      }
    }
    float bias = (lane < 36) ? breg[lane] : bcls[lane - 36];
    #pragma unroll
    for (int p = 0; p < 4; ++p)
      o54[pl0 + p][lane] = (s[p][0] + s[p][1]) + (s[p][2] + s[p][3]) + bias;
  }
  __syncthreads();

  if (tid < 144) {
    const int pl = tid / 9;
    const int a  = tid - pl * 9;
    const int pix = pix0 + pl;
    const int b = pix / 2500;
    const int n = pix - b * 2500;
    const int y = n / 50, x = n - y * 50;
    float d0 = o54[pl][a * 4 + 0], d1 = o54[pl][a * 4 + 1];
    float d2 = o54[pl][a * 4 + 2], d3 = o54[pl][a * 4 + 3];
    float sc0 = o54[pl][36 + a * 2], sc1 = o54[pl][36 + a * 2 + 1];
    float mx = fmaxf(sc0, sc1);
    float e0 = expf(sc0 - mx), e1 = expf(sc1 - mx);
    float fg = e1 / (e0 + e1);
    const int ri = a / 3;
    const int si = a - ri * 3;
    float sv = (si == 0) ? 8.f : (si == 1 ? 16.f : 32.f);
    float sqr_r  = (ri == 0) ? 0.70710678f : (ri == 1 ? 1.f : 1.41421356f);
    float sqr_ir = (ri == 0) ? 1.41421356f : (ri == 1 ? 1.f : 0.70710678f);
    float hh = 16.f * sv * sqr_r;
    float ww = 16.f * sv * sqr_ir;
    float acy = 16.f * (float)(y + 1) - 25.f;
    float acx = 16.f * (float)(x + 1) - 25.f;
    float ay1 = acy - 0.5f * hh, ay2 = acy + 0.5f * hh;
    float ax1 = acx - 0.5f * ww, ax2 = acx + 0.5f * ww;
    float ah = ay2 - ay1, aw = ax2 - ax1;
    float cy0 = ay1 + 0.5f * ah, cx0 = ax1 + 0.5f * aw;
    float cy = d0 * ah + cy0, cx = d1 * aw + cx0;
    float bh = expf(d2) * ah, bw = expf(d3) * aw;
    float y1 = cy - 0.5f * bh, x1 = cx - 0.5f * bw;
    float y2 = cy + 0.5f * bh, x2 = cx + 0.5f * bw;
    y1 = fminf(fmaxf(y1, 0.f), 800.f); y2 = fminf(fmaxf(y2, 0.f), 800.f);
    x1 = fminf(fmaxf(x1, 0.f), 800.f); x2 = fminf(fmaxf(x2, 0.f), 800.f);
    bool ok = ((y2 - y1) >= 16.f) && ((x2 - x1) >= 16.f);
    int gi = b * 22500 + n * 9 + a;
    ((float4*)boxes)[gi] = make_float4(y1, x1, y2, x2);
    scores[gi] = (ok && fg == fg) ? fg : NEGV;
  }
}

// ------------------------------------------------------------------
// Top-6000 radix select — per-wave histograms (verbatim r15, verified)
// ------------------------------------------------------------------
__global__ __launch_bounds__(1024) void topk_kernel(
    const float* __restrict__ scores, const float* __restrict__ boxes,
    float* __restrict__ tsc, float* __restrict__ tbx, int* __restrict__ tidx) {
  const int b = blockIdx.x, tid = threadIdx.x;
  __shared__ unsigned hist[16][256];
  __shared__ unsigned long long sh_pref;
  __shared__ unsigned sh_rem, sh_cnt;
  const int wid = tid >> 6;
  const float* sc = scores + b * 22500;
  if (tid == 0) { sh_pref = 0ull; sh_rem = 6000u; }
  __syncthreads();
  for (int pass = 0; pass < 6; ++pass) {
    const int shift = 40 - pass * 8;
    #pragma unroll
    for (int i = tid; i < 4096; i += 1024) ((unsigned*)hist)[i] = 0u;
    __syncthreads();
    const unsigned long long pref = sh_pref;
    for (int j = tid; j < 22500; j += 1024) {
      unsigned long long key = key48(sc[j], j);
      if ((key >> (shift + 8)) == pref)
        atomicAdd(&hist[wid][(unsigned)(key >> shift) & 255u], 1u);
    }
    __syncthreads();
    if (tid < 256) {
      unsigned s = 0;
      #pragma unroll
      for (int w = 0; w < 16; ++w) s += hist[w][tid];
      hist[0][tid] = s;
    }
    __syncthreads();
    if (tid == 0) {
      unsigned rem = sh_rem;
      unsigned c = 0; int sel = 0;
      for (int bin = 255; bin >= 0; --bin) {
        unsigned nc = c + hist[0][bin];
        if (nc >= rem) { sel = bin; break; }
        c = nc;
      }
      sh_rem = rem - c;
      sh_pref = (sh_pref << 8) | (unsigned long long)sel;
    }
    __syncthreads();
  }
  const unsigned long long T = sh_pref;
  if (tid == 0) sh_cnt = 0u;
  __syncthreads();
  const float4* bx4 = (const float4*)boxes;
  float4* tb4 = (float4*)tbx;
  for (int j = tid; j < 22500; j += 1024) {
    unsigned long long key = key48(sc[j], j);
    if (key >= T) {
      unsigned slot = atomicAdd(&sh_cnt, 1u);
      if (slot < 6000u) {
        tsc[b * 6000 + slot] = sc[j];
        tidx[b * 6000 + slot] = j;
        tb4[b * 6000 + slot] = bx4[b * 22500 + j];
      }
    }
  }
}

// ------------------------------------------------------------------
// Rank-sort v2: keys staged in LDS, inner loop reads the SAME address
// across all lanes (hardware broadcast, conflict-free) — replaces the
// 2x ds_bpermute-per-key shfl loop. Same comparisons -> same ranks.
// ------------------------------------------------------------------
__global__ __launch_bounds__(256) void rank_kernel(
    const float* __restrict__ tsc, const int* __restrict__ tidx,
    const float* __restrict__ tbx,
    float* __restrict__ sbx, float* __restrict__ ssc) {
  __shared__ unsigned long long keys[6000];
  const int b = blockIdx.y;
  const int tid = threadIdx.x;
  const int c = blockIdx.x * 256 + tid;
  const float* scb = tsc + b * 6000;
  const int* idb = tidx + b * 6000;
  for (int j = tid; j < 6000; j += 256)
    keys[j] = key48(scb[j], idb[j]);
  __syncthreads();
  unsigned long long kc = (c < 6000) ? keys[c] : ~0ull;
  int rank = 0;
  #pragma unroll 4
  for (int j = 0; j < 6000; ++j)
    rank += (keys[j] > kc) ? 1 : 0;
  if (c < 6000) {
    ((float4*)sbx)[b * 6000 + rank] = ((const float4*)tbx)[b * 6000 + c];
    ssc[b * 6000 + rank] = scb[c];
  }
}

// ------------------------------------------------------------------
// Suppression bitmask (verbatim, verified)
// ------------------------------------------------------------------
__global__ __launch_bounds__(256) void mask_kernel(
    const float* __restrict__ sbx, unsigned long long* __restrict__ mask) {
  const int b = blockIdx.y;
  const int row = blockIdx.x * 64 + (threadIdx.x & 63);
  const int wseg = threadIdx.x >> 6;
  __shared__ float4 jb[512];
  const float4* sb4 = (const float4*)sbx + (size_t)b * 6000;
  float4 rb = sb4[row < 6000 ? row : 5999];
  const float ra = (rb.z - rb.x) * (rb.w - rb.y);
  unsigned long long m[24];
  #pragma unroll
  for (int q = 0; q < 24; ++q) m[q] = 0ull;
  for (int jt = 0; jt < 12; ++jt) {
    __syncthreads();
    for (int s = threadIdx.x; s < 512; s += 256) {
      int j = jt * 512 + s;
      jb[s] = (j < 6000) ? sb4[j] : make_float4(0.f, 0.f, 0.f, 0.f);
    }
    __syncthreads();
    #pragma unroll
    for (int ww = 0; ww < 2; ++ww) {
      int w = jt * 8 + wseg * 2 + ww;
      if (w >= 94) continue;
      int j0 = (wseg * 2 + ww) * 64;
      unsigned long long bits = 0ull;
      #pragma unroll
      for (int u = 0; u < 64; ++u) {
        float4 bb = jb[j0 + u];
        float aj = (bb.z - bb.x) * (bb.w - bb.y);
        float yy1 = fmaxf(rb.x, bb.x), xx1 = fmaxf(rb.y, bb.y);
        float yy2 = fminf(rb.z, bb.z), xx2 = fminf(rb.w, bb.w);
        float inter = fmaxf(yy2 - yy1, 0.f) * fmaxf(xx2 - xx1, 0.f);
        float iou = inter / (((ra + aj) - inter) + 1e-9f);
        bits |= (iou > 0.7f) ? (1ull << u) : 0ull;
      }
      m[jt * 2 + ww] = bits;
    }
  }
  if (row < 6000) {
    unsigned long long* mr = mask + (size_t)(b * 6000 + row) * 94;
    #pragma unroll
    for (int jt = 0; jt < 12; ++jt)
      #pragma unroll
      for (int ww = 0; ww < 2; ++ww) {
        int w = jt * 8 + wseg * 2 + ww;
        if (w < 94) mr[w] = m[jt * 2 + ww];
      }
  }
}

// ------------------------------------------------------------------
// Greedy bitmask walk, chunked + 4-wide ILP apply (verbatim r15)
// ------------------------------------------------------------------
__global__ __launch_bounds__(64) void nmsbit_kernel(
    const float* __restrict__ ssc, const float* __restrict__ sbx,
    const unsigned long long* __restrict__ mask, float* __restrict__ out) {
  const int b = blockIdx.x, lane = threadIdx.x;
  __shared__ unsigned long long live[94];
  __shared__ int picks[300];
  const unsigned long long* mbase = mask + (size_t)b * 6000 * 94;
  int cnt = 0;
  for (int j = lane; j < 6000; j += 64)
    cnt += (ssc[b * 6000 + j] > NEGH) ? 1 : 0;
  #pragma unroll
  for (int off = 32; off > 0; off >>= 1) cnt += __shfl_down(cnt, off);
  const int nvalid = __shfl(cnt, 0);
  for (int w = lane; w < 94; w += 64) {
    int base = w * 64;
    unsigned long long mm;
    if (base + 64 <= nvalid) mm = ~0ull;
    else if (base >= nvalid) mm = 0ull;
    else mm = (~0ull) >> (64 - (nvalid - base));
    live[w] = mm;
  }
  __syncthreads();

  int np = 0;
  for (int c = 0; c < 94 && np < 300; ++c) {
    unsigned long long bits = live[c];
    if (bits == 0ull) continue;
    int row = c * 64 + lane;
    unsigned long long dw = (row < 6000) ? mbase[(size_t)row * 94 + c] : 0ull;
    unsigned long long prows = 0ull;
    while (bits != 0ull && np < 300) {
      int bpos = __ffsll(bits) - 1;
      if (lane == 0) picks[np] = c * 64 + bpos;
      np++;
      prows |= (1ull << bpos);
      unsigned long long dwb = __shfl(dw, bpos);
      bits &= ~dwb;
      bits &= ~(1ull << bpos);
    }
    unsigned long long acc0 = 0ull, acc1 = 0ull;
    unsigned long long pr = prows;
    while (pr != 0ull) {
      int r0, r1 = -1, r2 = -1, r3 = -1;
      r0 = __ffsll(pr) - 1; pr &= pr - 1ull;
      if (pr) { r1 = __ffsll(pr) - 1; pr &= pr - 1ull; }
      if (r1 >= 0 && pr) { r2 = __ffsll(pr) - 1; pr &= pr - 1ull; }
      if (r2 >= 0 && pr) { r3 = __ffsll(pr) - 1; pr &= pr - 1ull; }
      const unsigned long long* q0 = mbase + (size_t)(c * 64 + r0) * 94;
      unsigned long long a0 = q0[lane];
      unsigned long long a1 = (lane < 30) ? q0[lane + 64] : 0ull;
      unsigned long long b0 = 0ull, b1 = 0ull, c0 = 0ull, c1 = 0ull,
                         d0 = 0ull, d1 = 0ull;
      if (r1 >= 0) {
        const unsigned long long* q = mbase + (size_t)(c * 64 + r1) * 94;
        b0 = q[lane]; b1 = (lane < 30) ? q[lane + 64] : 0ull;
      }
      if (r2 >= 0) {
        const unsigned long long* q = mbase + (size_t)(c * 64 + r2) * 94;
        c0 = q[lane]; c1 = (lane < 30) ? q[lane + 64] : 0ull;
      }
      if (r3 >= 0) {
        const unsigned long long* q = mbase + (size_t)(c * 64 + r3) * 94;
        d0 = q[lane]; d1 = (lane < 30) ? q[lane + 64] : 0ull;
      }
      acc0 |= (a0 | b0) | (c0 | d0);
      acc1 |= (a1 | b1) | (c1 | d1);
    }
    if (prows != 0ull) {
      live[lane] &= ~acc0;
      if (lane < 30) live[lane + 64] &= ~acc1;
      __syncthreads();
    }
  }
  __syncthreads();

  float* rois = out;
  float* rsc  = out + 12000;
  for (int t = lane; t < 300; t += 64) {
    float* rp = rois + (size_t)(b * 300 + t) * 5;
    if (t < np) {
      int i = picks[t];
      float4 bb = ((const float4*)sbx)[b * 6000 + i];
      rp[0] = (float)b; rp[1] = bb.x; rp[2] = bb.y; rp[3] = bb.z; rp[4] = bb.w;
      rsc[b * 300 + t] = ssc[b * 6000 + i];
    } else {
      rp[0] = 0.f; rp[1] = 0.f; rp[2] = 0.f; rp[3] = 0.f; rp[4] = 0.f;
      rsc[b * 300 + t] = 0.f;
    }
  }
}

// ------------------------------------------------------------------
extern "C" void kernel_launch(void* const* d_in, const int* in_sizes, int n_in,
                              void* d_out, int out_size, void* d_ws, size_t ws_size,
                              hipStream_t stream) {
  const float* feat = (const float*)d_in[0];
  const float* W1   = (const float*)d_in[1];
  const float* b1   = (const float*)d_in[2];
  const float* Wreg = (const float*)d_in[3];
  const float* breg = (const float*)d_in[4];
  const float* Wcls = (const float*)d_in[5];
  const float* bcls = (const float*)d_in[6];
  float* out = (float*)d_out;
  float* ws  = (float*)d_ws;

  const size_t NEED = 59978368ull;
  if (ws_size >= NEED) {
    unsigned* W1pack = (unsigned*)ws;
    float* conv1  = ws + 3538944;
    unsigned long long* mask = (unsigned long long*)(ws + 3538944);
    float* boxes  = ws + 13778944;
    float* sbx    = ws + 13778944;
    float* ssc    = ws + 13970944;
    float* scores = ws + 14498944;
    float* tbx    = ws + 14678944;
    float* tsc    = ws + 14870944;
    int*   tidx   = (int*)(ws + 14918944);
    float* Wt     = ws + 14966944;

    w1pack_kernel<<<512, 256, 0, stream>>>(W1, W1pack);
    wtpack_kernel<<<108, 256, 0, stream>>>(Wreg, Wcls, Wt);
    conv_mfma_kernel<<<dim3(20, 4, 8), 256, 0, stream>>>(feat, (const char*)W1pack, b1, conv1);
    heads_kernel<<<1250, 256, 0, stream>>>(conv1, Wt, breg, bcls, boxes, scores);
    topk_kernel<<<8, 1024, 0, stream>>>(scores, boxes, tsc, tbx, tidx);
    rank_kernel<<<dim3(24, 8), 256, 0, stream>>>(tsc, tidx, tbx, sbx, ssc);
    mask_kernel<<<dim3(94, 8), 256, 0, stream>>>(sbx, mask);
    nmsbit_kernel<<<8, 64, 0, stream>>>(ssc, sbx, mask, out);
  }
}

// Round 17
// 1317.143 us; speedup vs baseline: 1.1801x; 1.0299x over previous
//
#include <hip/hip_runtime.h>
#include <hip/hip_bf16.h>
#include <math.h>

#define NEGV -1e9f
#define NEGH -5e8f

typedef __attribute__((ext_vector_type(8))) short short8;
typedef __attribute__((ext_vector_type(4))) float f32x4;

__device__ __forceinline__ unsigned fkey(float f) {
  unsigned u = __float_as_uint(f);
  return (u & 0x80000000u) ? ~u : (u | 0x80000000u);
}
__device__ __forceinline__ unsigned long long key48(float s, int j) {
  return ((unsigned long long)fkey(s) << 15) | (unsigned long long)(32767 - j);
}
__device__ __forceinline__ unsigned short bf16_rne(float v) {
  unsigned u = __float_as_uint(v);
  unsigned r = u + 0x7FFFu + ((u >> 16) & 1u);
  return (unsigned short)(r >> 16);
}
__device__ __forceinline__ float bf16_f(unsigned short h) {
  return __uint_as_float(((unsigned)h) << 16);
}

#if defined(__has_builtin)
#if __has_builtin(__builtin_amdgcn_global_load_lds)
#define HAS_GLL 1
#endif
#endif

__device__ __forceinline__ void stage16(const char* gsrc_lane, char* ldsbase, int ln) {
#ifdef HAS_GLL
  typedef unsigned int __attribute__((address_space(1))) gu32;
  typedef unsigned int __attribute__((address_space(3))) lu32;
  __builtin_amdgcn_global_load_lds((const gu32*)gsrc_lane, (lu32*)ldsbase, 16, 0, 0);
#else
  *(uint4*)(ldsbase + ln * 16) = *(const uint4*)gsrc_lane;
#endif
}

// ==================================================================
// Packed-tile byte layout (per plane: rowpairs x 128B):
//   byte(row,k) = (row>>1)*128 + ((((row&1)<<6) + 2k) ^ (((row>>1)&7)<<4))
// W1pack image order: [ct=4][s=144][plane hi/mid/lo][2048 dw]
// K-order: TAP-MAJOR — FROZEN (r11: accumulation-order changes cascade
// through NMS ties into absmax 800). conv1 bitwise = r5-r16 lineage.
// TRIANGLE MASK (r17): greedy walk consumes only words w >= row-chunk;
// lower-triangle mask words are dead -> not computed, not read.
// ==================================================================

// ------------------------------------------------------------------
// Pack W1 (coalesced, verbatim r12-r16 — bytes verified identical).
// ------------------------------------------------------------------
__global__ __launch_bounds__(256) void w1pack_kernel(
    const float* __restrict__ W1, unsigned* __restrict__ W1pack) {
  int g = blockIdx.x * 256 + threadIdx.x;   // 512*256 = 131072 exact
  int oc = g >> 8;
  int cp = g & 255;
  int cin = cp * 2;
  int ct = oc >> 7;
  int row = oc & 127;
  float buf[18];
  const float* src = W1 + (size_t)oc * 4608 + cin * 9;
  #pragma unroll
  for (int i = 0; i < 18; ++i) buf[i] = src[i];
  int k = cin & 31;
  int R = row >> 1;
  int val = ((row & 1) << 6) | (k << 1);
  int tb = (R << 7) | (val ^ ((R & 7) << 4));
  int dwimg = tb >> 2;
  int sBase = cp >> 4;                      // cin>>5
  #pragma unroll
  for (int tap = 0; tap < 9; ++tap) {
    float w0 = buf[tap], w1 = buf[9 + tap];
    unsigned short h0 = bf16_rne(w0), h1 = bf16_rne(w1);
    float r0 = w0 - bf16_f(h0), r1 = w1 - bf16_f(h1);
    unsigned short m0 = bf16_rne(r0), m1 = bf16_rne(r1);
    unsigned short l0 = bf16_rne(r0 - bf16_f(m0)), l1 = bf16_rne(r1 - bf16_f(m1));
    int s = tap * 16 + sBase;               // tap-major (frozen)
    size_t base = ((size_t)(ct * 144 + s) * 3) * 2048 + dwimg;
    W1pack[base]        = (unsigned)h0 | ((unsigned)h1 << 16);
    W1pack[base + 2048] = (unsigned)m0 | ((unsigned)m1 << 16);
    W1pack[base + 4096] = (unsigned)l0 | ((unsigned)l1 << 16);
  }
}

// ------------------------------------------------------------------
// Heads weight transpose v2 (verbatim r16, verified)
// ------------------------------------------------------------------
__global__ __launch_bounds__(256) void wtpack_kernel(
    const float* __restrict__ Wreg, const float* __restrict__ Wcls,
    float* __restrict__ Wt) {
  int i = blockIdx.x * 256 + threadIdx.x;   // 108*256 = 27648 exact
  int gg = i / 216;
  int r  = i - gg * 216;
  int j  = r >> 2;
  int c  = gg * 4 + (r & 3);
  Wt[i] = (j < 36) ? Wreg[j * 512 + c] : Wcls[(j - 36) * 512 + c];
}

// ------------------------------------------------------------------
// Conv 3x3 split-3 bf16 MFMA GEMM — verbatim BEST-MEASURED (frozen).
// ------------------------------------------------------------------
__global__ __launch_bounds__(256) void conv_mfma_kernel(
    const float* __restrict__ feat, const char* __restrict__ W1pack,
    const float* __restrict__ b1, float* __restrict__ conv1) {
  __shared__ char smem[49152];
  const int tid = threadIdx.x;
  const int b  = blockIdx.z;
  const int ct = blockIdx.y;
  const int n0 = blockIdx.x * 128;
  const int wv = tid >> 6, ln = tid & 63;

  const int spix = tid & 127;
  const int kh   = tid >> 7;
  int p = n0 + spix; if (p > 2499) p = 2499;
  const int pyy = p / 50;
  const int pxx = p - pyy * 50;
  const float* featb = feat + (size_t)b * 512 * 2500;
  const char* wsrc = W1pack + (size_t)ct * 144 * 24576;

  const int wch0  = (wv >> 1) * 64;
  const int wpix0 = (wv & 1) * 64;
  const int lrow = ln & 15, lg = ln >> 4;

  f32x4 acc[4][4];
  #pragma unroll
  for (int i = 0; i < 4; ++i)
    #pragma unroll
    for (int j = 0; j < 4; ++j) acc[i][j] = (f32x4)0.f;

  float u[16];

  auto loadFeat = [&](int s) {
    int tap = s >> 4;
    int dy = tap / 3, dx = tap - dy * 3;
    int iy = pyy + dy - 1, ix = pxx + dx - 1;
    bool ok = ((unsigned)iy < 50u) && ((unsigned)ix < 50u);
    int cinb = ((s & 15) << 5) + kh * 16;
    const float* base = featb + (size_t)cinb * 2500 + iy * 50 + ix;
    #pragma unroll
    for (int i = 0; i < 16; ++i) u[i] = ok ? base[(size_t)i * 2500] : 0.f;
  };
  auto issueA = [&](int s) {
    const char* src = wsrc + (size_t)s * 24576;
    char* lbase = smem + (tid >> 6) * 1024;
    #pragma unroll
    for (int c = 0; c < 6; ++c)
      stage16(src + c * 4096 + tid * 16, lbase + c * 4096, ln);
  };
  auto writeB = [&]() {
    unsigned short h[16], m[16], l[16];
    #pragma unroll
    for (int i = 0; i < 16; ++i) {
      float v = u[i];
      h[i] = bf16_rne(v);
      float r1 = v - bf16_f(h[i]);
      m[i] = bf16_rne(r1);
      float r2 = r1 - bf16_f(m[i]);
      l[i] = bf16_rne(r2);
    }
    const int r = spix >> 1;
    const int swz = (r & 7) << 4;
    char* rowb = smem + 24576 + r * 128;
    #pragma unroll
    for (int pl = 0; pl < 3; ++pl) {
      const unsigned short* sp = (pl == 0) ? h : (pl == 1 ? m : l);
      char* pb = rowb + pl * 8192;
      #pragma unroll
      for (int q = 0; q < 4; ++q) {
        int pre = ((spix & 1) << 6) + kh * 32 + q * 8;
        uint2 w;
        w.x = (unsigned)sp[q*4]   | ((unsigned)sp[q*4+1] << 16);
        w.y = (unsigned)sp[q*4+2] | ((unsigned)sp[q*4+3] << 16);
        *(uint2*)(pb + (pre ^ swz)) = w;
      }
    }
  };
  auto rdFrag = [&](const char* base, int row) -> short8 {
    int byte = (row >> 1) * 128 +
               ((((row & 1) << 6) + (lg << 4)) ^ (((row >> 1) & 7) << 4));
    return *(const short8*)(base + byte);
  };

  loadFeat(0);
  #pragma unroll 1
  for (int s = 0; s < 144; ++s) {
    __syncthreads();
    issueA(s);
    writeB();
    __syncthreads();
    if (s + 1 < 144) loadFeat(s + 1);
    short8 fa[3][4];
    #pragma unroll
    for (int pl = 0; pl < 3; ++pl)
      #pragma unroll
      for (int f = 0; f < 4; ++f)
        fa[pl][f] = rdFrag(smem + pl * 8192, wch0 + f * 16 + lrow);
    #pragma unroll
    for (int jb = 0; jb < 3; ++jb) {
      short8 fb[4];
      #pragma unroll
      for (int f = 0; f < 4; ++f)
        fb[f] = rdFrag(smem + 24576 + jb * 8192, wpix0 + f * 16 + lrow);
      const int na = 3 - jb;
      #pragma unroll
      for (int ap = 0; ap < 3; ++ap) {
        if (ap < na) {
          #pragma unroll
          for (int i = 0; i < 4; ++i)
            #pragma unroll
            for (int j = 0; j < 4; ++j)
              acc[i][j] = __builtin_amdgcn_mfma_f32_16x16x32_bf16(
                  fa[ap][i], fb[j], acc[i][j], 0, 0, 0);
        }
      }
    }
  }

  const int chb = ct * 128 + wch0 + lg * 4;
  #pragma unroll
  for (int i = 0; i < 4; ++i) {
    int ch = chb + i * 16;
    float4 bias = *(const float4*)&b1[ch];
    #pragma unroll
    for (int j = 0; j < 4; ++j) {
      int pix = n0 + wpix0 + j * 16 + lrow;
      if (pix < 2500) {
        float4 o;
        o.x = fmaxf(acc[i][j][0] + bias.x, 0.f);
        o.y = fmaxf(acc[i][j][1] + bias.y, 0.f);
        o.z = fmaxf(acc[i][j][2] + bias.z, 0.f);
        o.w = fmaxf(acc[i][j][3] + bias.w, 0.f);
        *(float4*)&conv1[(size_t)(b * 2500 + pix) * 512 + ch] = o;
      }
    }
  }
}

// ------------------------------------------------------------------
// Heads v3 (verbatim r16, verified)
// ------------------------------------------------------------------
__global__ __launch_bounds__(256) void heads_kernel(
    const float* __restrict__ conv1, const float* __restrict__ Wt,
    const float* __restrict__ breg, const float* __restrict__ bcls,
    float* __restrict__ boxes, float* __restrict__ scores) {
  __shared__ float v[16][512];
  __shared__ float o54[16][56];
  const int tid = threadIdx.x;
  const int wvi = tid >> 6, lane = tid & 63;
  const int pix0 = blockIdx.x * 16;
  float4* vf = (float4*)v;
  const float4* src4 = (const float4*)(conv1 + (size_t)pix0 * 512);
  #pragma unroll
  for (int i = 0; i < 8; ++i) vf[i * 256 + tid] = src4[i * 256 + tid];
  __syncthreads();

  if (lane < 54) {
    float s[4][4];
    #pragma unroll
    for (int p = 0; p < 4; ++p)
      #pragma unroll
      for (int q = 0; q < 4; ++q) s[p][q] = 0.f;
    const int pl0 = wvi * 4;
    for (int c = 0; c < 512; c += 4) {
      float4 w = *(const float4*)&Wt[(c >> 2) * 216 + lane * 4];
      #pragma unroll
      for (int p = 0; p < 4; ++p) {
        s[p][0] = fmaf(v[pl0 + p][c],     w.x, s[p][0]);
        s[p][1] = fmaf(v[pl0 + p][c + 1], w.y, s[p][1]);
        s[p][2] = fmaf(v[pl0 + p][c + 2], w.z, s[p][2]);
        s[p][3] = fmaf(v[pl0 + p][c + 3], w.w, s[p][3]);
      }
    }
    float bias = (lane < 36) ? breg[lane] : bcls[lane - 36];
    #pragma unroll
    for (int p = 0; p < 4; ++p)
      o54[pl0 + p][lane] = (s[p][0] + s[p][1]) + (s[p][2] + s[p][3]) + bias;
  }
  __syncthreads();

  if (tid < 144) {
    const int pl = tid / 9;
    const int a  = tid - pl * 9;
    const int pix = pix0 + pl;
    const int b = pix / 2500;
    const int n = pix - b * 2500;
    const int y = n / 50, x = n - y * 50;
    float d0 = o54[pl][a * 4 + 0], d1 = o54[pl][a * 4 + 1];
    float d2 = o54[pl][a * 4 + 2], d3 = o54[pl][a * 4 + 3];
    float sc0 = o54[pl][36 + a * 2], sc1 = o54[pl][36 + a * 2 + 1];
    float mx = fmaxf(sc0, sc1);
    float e0 = expf(sc0 - mx), e1 = expf(sc1 - mx);
    float fg = e1 / (e0 + e1);
    const int ri = a / 3;
    const int si = a - ri * 3;
    float sv = (si == 0) ? 8.f : (si == 1 ? 16.f : 32.f);
    float sqr_r  = (ri == 0) ? 0.70710678f : (ri == 1 ? 1.f : 1.41421356f);
    float sqr_ir = (ri == 0) ? 1.41421356f : (ri == 1 ? 1.f : 0.70710678f);
    float hh = 16.f * sv * sqr_r;
    float ww = 16.f * sv * sqr_ir;
    float acy = 16.f * (float)(y + 1) - 25.f;
    float acx = 16.f * (float)(x + 1) - 25.f;
    float ay1 = acy - 0.5f * hh, ay2 = acy + 0.5f * hh;
    float ax1 = acx - 0.5f * ww, ax2 = acx + 0.5f * ww;
    float ah = ay2 - ay1, aw = ax2 - ax1;
    float cy0 = ay1 + 0.5f * ah, cx0 = ax1 + 0.5f * aw;
    float cy = d0 * ah + cy0, cx = d1 * aw + cx0;
    float bh = expf(d2) * ah, bw = expf(d3) * aw;
    float y1 = cy - 0.5f * bh, x1 = cx - 0.5f * bw;
    float y2 = cy + 0.5f * bh, x2 = cx + 0.5f * bw;
    y1 = fminf(fmaxf(y1, 0.f), 800.f); y2 = fminf(fmaxf(y2, 0.f), 800.f);
    x1 = fminf(fmaxf(x1, 0.f), 800.f); x2 = fminf(fmaxf(x2, 0.f), 800.f);
    bool ok = ((y2 - y1) >= 16.f) && ((x2 - x1) >= 16.f);
    int gi = b * 22500 + n * 9 + a;
    ((float4*)boxes)[gi] = make_float4(y1, x1, y2, x2);
    scores[gi] = (ok && fg == fg) ? fg : NEGV;
  }
}

// ------------------------------------------------------------------
// Top-6000 radix select — per-wave histograms (verbatim r15/16)
// ------------------------------------------------------------------
__global__ __launch_bounds__(1024) void topk_kernel(
    const float* __restrict__ scores, const float* __restrict__ boxes,
    float* __restrict__ tsc, float* __restrict__ tbx, int* __restrict__ tidx) {
  const int b = blockIdx.x, tid = threadIdx.x;
  __shared__ unsigned hist[16][256];
  __shared__ unsigned long long sh_pref;
  __shared__ unsigned sh_rem, sh_cnt;
  const int wid = tid >> 6;
  const float* sc = scores + b * 22500;
  if (tid == 0) { sh_pref = 0ull; sh_rem = 6000u; }
  __syncthreads();
  for (int pass = 0; pass < 6; ++pass) {
    const int shift = 40 - pass * 8;
    #pragma unroll
    for (int i = tid; i < 4096; i += 1024) ((unsigned*)hist)[i] = 0u;
    __syncthreads();
    const unsigned long long pref = sh_pref;
    for (int j = tid; j < 22500; j += 1024) {
      unsigned long long key = key48(sc[j], j);
      if ((key >> (shift + 8)) == pref)
        atomicAdd(&hist[wid][(unsigned)(key >> shift) & 255u], 1u);
    }
    __syncthreads();
    if (tid < 256) {
      unsigned s = 0;
      #pragma unroll
      for (int w = 0; w < 16; ++w) s += hist[w][tid];
      hist[0][tid] = s;
    }
    __syncthreads();
    if (tid == 0) {
      unsigned rem = sh_rem;
      unsigned c = 0; int sel = 0;
      for (int bin = 255; bin >= 0; --bin) {
        unsigned nc = c + hist[0][bin];
        if (nc >= rem) { sel = bin; break; }
        c = nc;
      }
      sh_rem = rem - c;
      sh_pref = (sh_pref << 8) | (unsigned long long)sel;
    }
    __syncthreads();
  }
  const unsigned long long T = sh_pref;
  if (tid == 0) sh_cnt = 0u;
  __syncthreads();
  const float4* bx4 = (const float4*)boxes;
  float4* tb4 = (float4*)tbx;
  for (int j = tid; j < 22500; j += 1024) {
    unsigned long long key = key48(sc[j], j);
    if (key >= T) {
      unsigned slot = atomicAdd(&sh_cnt, 1u);
      if (slot < 6000u) {
        tsc[b * 6000 + slot] = sc[j];
        tidx[b * 6000 + slot] = j;
        tb4[b * 6000 + slot] = bx4[b * 22500 + j];
      }
    }
  }
}

// ------------------------------------------------------------------
// Rank-sort v2 (verbatim r16, verified)
// ------------------------------------------------------------------
__global__ __launch_bounds__(256) void rank_kernel(
    const float* __restrict__ tsc, const int* __restrict__ tidx,
    const float* __restrict__ tbx,
    float* __restrict__ sbx, float* __restrict__ ssc) {
  __shared__ unsigned long long keys[6000];
  const int b = blockIdx.y;
  const int tid = threadIdx.x;
  const int c = blockIdx.x * 256 + tid;
  const float* scb = tsc + b * 6000;
  const int* idb = tidx + b * 6000;
  for (int j = tid; j < 6000; j += 256)
    keys[j] = key48(scb[j], idb[j]);
  __syncthreads();
  unsigned long long kc = (c < 6000) ? keys[c] : ~0ull;
  int rank = 0;
  #pragma unroll 4
  for (int j = 0; j < 6000; ++j)
    rank += (keys[j] > kc) ? 1 : 0;
  if (c < 6000) {
    ((float4*)sbx)[b * 6000 + rank] = ((const float4*)tbx)[b * 6000 + c];
    ssc[b * 6000 + rank] = scb[c];
  }
}

// ------------------------------------------------------------------
// Suppression bitmask — TRIANGLE: only words w >= block's chunk c0
// are computed/written (lower-triangle words are provably dead).
// ------------------------------------------------------------------
__global__ __launch_bounds__(256) void mask_kernel(
    const float* __restrict__ sbx, unsigned long long* __restrict__ mask) {
  const int b = blockIdx.y;
  const int c0 = blockIdx.x;                         // chunk of these rows
  const int row = c0 * 64 + (threadIdx.x & 63);
  const int wseg = threadIdx.x >> 6;
  __shared__ float4 jb[512];
  const float4* sb4 = (const float4*)sbx + (size_t)b * 6000;
  float4 rb = sb4[row < 6000 ? row : 5999];
  const float ra = (rb.z - rb.x) * (rb.w - rb.y);
  unsigned long long m[24];
  #pragma unroll
  for (int q = 0; q < 24; ++q) m[q] = 0ull;
  const int jt0 = c0 >> 3;                           // first tile with w >= c0
  for (int jt = jt0; jt < 12; ++jt) {
    __syncthreads();
    for (int s = threadIdx.x; s < 512; s += 256) {
      int j = jt * 512 + s;
      jb[s] = (j < 6000) ? sb4[j] : make_float4(0.f, 0.f, 0.f, 0.f);
    }
    __syncthreads();
    #pragma unroll
    for (int ww = 0; ww < 2; ++ww) {
      int w = jt * 8 + wseg * 2 + ww;
      if (w >= 94 || w < c0) continue;
      int j0 = (wseg * 2 + ww) * 64;
      unsigned long long bits = 0ull;
      #pragma unroll
      for (int u = 0; u < 64; ++u) {
        float4 bb = jb[j0 + u];
        float aj = (bb.z - bb.x) * (bb.w - bb.y);
        float yy1 = fmaxf(rb.x, bb.x), xx1 = fmaxf(rb.y, bb.y);
        float yy2 = fminf(rb.z, bb.z), xx2 = fminf(rb.w, bb.w);
        float inter = fmaxf(yy2 - yy1, 0.f) * fmaxf(xx2 - xx1, 0.f);
        float iou = inter / (((ra + aj) - inter) + 1e-9f);
        bits |= (iou > 0.7f) ? (1ull << u) : 0ull;
      }
      m[jt * 2 + ww] = bits;
    }
  }
  if (row < 6000) {
    unsigned long long* mr = mask + (size_t)(b * 6000 + row) * 94;
    #pragma unroll
    for (int jt = 0; jt < 12; ++jt)
      #pragma unroll
      for (int ww = 0; ww < 2; ++ww) {
        int w = jt * 8 + wseg * 2 + ww;
        if (w < 94 && w >= c0) mr[w] = m[jt * 2 + ww];
      }
  }
}

// ------------------------------------------------------------------
// Greedy bitmask walk, chunked + 4-wide ILP apply; reads only words
// >= current chunk (skipped words contribute OR-identity 0 and their
// live[] targets are never read again -> identical picks).
// ------------------------------------------------------------------
__global__ __launch_bounds__(64) void nmsbit_kernel(
    const float* __restrict__ ssc, const float* __restrict__ sbx,
    const unsigned long long* __restrict__ mask, float* __restrict__ out) {
  const int b = blockIdx.x, lane = threadIdx.x;
  __shared__ unsigned long long live[94];
  __shared__ int picks[300];
  const unsigned long long* mbase = mask + (size_t)b * 6000 * 94;
  int cnt = 0;
  for (int j = lane; j < 6000; j += 64)
    cnt += (ssc[b * 6000 + j] > NEGH) ? 1 : 0;
  #pragma unroll
  for (int off = 32; off > 0; off >>= 1) cnt += __shfl_down(cnt, off);
  const int nvalid = __shfl(cnt, 0);
  for (int w = lane; w < 94; w += 64) {
    int base = w * 64;
    unsigned long long mm;
    if (base + 64 <= nvalid) mm = ~0ull;
    else if (base >= nvalid) mm = 0ull;
    else mm = (~0ull) >> (64 - (nvalid - base));
    live[w] = mm;
  }
  __syncthreads();

  int np = 0;
  for (int c = 0; c < 94 && np < 300; ++c) {
    unsigned long long bits = live[c];
    if (bits == 0ull) continue;
    int row = c * 64 + lane;
    unsigned long long dw = (row < 6000) ? mbase[(size_t)row * 94 + c] : 0ull;
    unsigned long long prows = 0ull;
    while (bits != 0ull && np < 300) {
      int bpos = __ffsll(bits) - 1;
      if (lane == 0) picks[np] = c * 64 + bpos;
      np++;
      prows |= (1ull << bpos);
      unsigned long long dwb = __shfl(dw, bpos);
      bits &= ~dwb;
      bits &= ~(1ull << bpos);
    }
    const bool g0 = (lane >= c);                  // word(lane)   >= c
    const bool g1 = (lane < 30) && (lane + 64 >= c);
    unsigned long long acc0 = 0ull, acc1 = 0ull;
    unsigned long long pr = prows;
    while (pr != 0ull) {
      int r0, r1 = -1, r2 = -1, r3 = -1;
      r0 = __ffsll(pr) - 1; pr &= pr - 1ull;
      if (pr) { r1 = __ffsll(pr) - 1; pr &= pr - 1ull; }
      if (r1 >= 0 && pr) { r2 = __ffsll(pr) - 1; pr &= pr - 1ull; }
      if (r2 >= 0 && pr) { r3 = __ffsll(pr) - 1; pr &= pr - 1ull; }
      const unsigned long long* q0 = mbase + (size_t)(c * 64 + r0) * 94;
      unsigned long long a0 = g0 ? q0[lane] : 0ull;
      unsigned long long a1 = g1 ? q0[lane + 64] : 0ull;
      unsigned long long b0 = 0ull, b1 = 0ull, c0_ = 0ull, c1 = 0ull,
                         d0 = 0ull, d1 = 0ull;
      if (r1 >= 0) {
        const unsigned long long* q = mbase + (size_t)(c * 64 + r1) * 94;
        b0 = g0 ? q[lane] : 0ull; b1 = g1 ? q[lane + 64] : 0ull;
      }
      if (r2 >= 0) {
        const unsigned long long* q = mbase + (size_t)(c * 64 + r2) * 94;
        c0_ = g0 ? q[lane] : 0ull; c1 = g1 ? q[lane + 64] : 0ull;
      }
      if (r3 >= 0) {
        const unsigned long long* q = mbase + (size_t)(c * 64 + r3) * 94;
        d0 = g0 ? q[lane] : 0ull; d1 = g1 ? q[lane + 64] : 0ull;
      }
      acc0 |= (a0 | b0) | (c0_ | d0);
      acc1 |= (a1 | b1) | (c1 | d1);
    }
    if (prows != 0ull) {
      live[lane] &= ~acc0;
      if (lane < 30) live[lane + 64] &= ~acc1;
      __syncthreads();
    }
  }
  __syncthreads();

  float* rois = out;
  float* rsc  = out + 12000;
  for (int t = lane; t < 300; t += 64) {
    float* rp = rois + (size_t)(b * 300 + t) * 5;
    if (t < np) {
      int i = picks[t];
      float4 bb = ((const float4*)sbx)[b * 6000 + i];
      rp[0] = (float)b; rp[1] = bb.x; rp[2] = bb.y; rp[3] = bb.z; rp[4] = bb.w;
      rsc[b * 300 + t] = ssc[b * 6000 + i];
    } else {
      rp[0] = 0.f; rp[1] = 0.f; rp[2] = 0.f; rp[3] = 0.f; rp[4] = 0.f;
      rsc[b * 300 + t] = 0.f;
    }
  }
}

// ------------------------------------------------------------------
extern "C" void kernel_launch(void* const* d_in, const int* in_sizes, int n_in,
                              void* d_out, int out_size, void* d_ws, size_t ws_size,
                              hipStream_t stream) {
  const float* feat = (const float*)d_in[0];
  const float* W1   = (const float*)d_in[1];
  const float* b1   = (const float*)d_in[2];
  const float* Wreg = (const float*)d_in[3];
  const float* breg = (const float*)d_in[4];
  const float* Wcls = (const float*)d_in[5];
  const float* bcls = (const float*)d_in[6];
  float* out = (float*)d_out;
  float* ws  = (float*)d_ws;

  const size_t NEED = 59978368ull;
  if (ws_size >= NEED) {
    unsigned* W1pack = (unsigned*)ws;
    float* conv1  = ws + 3538944;
    unsigned long long* mask = (unsigned long long*)(ws + 3538944);
    float* boxes  = ws + 13778944;
    float* sbx    = ws + 13778944;
    float* ssc    = ws + 13970944;
    float* scores = ws + 14498944;
    float* tbx    = ws + 14678944;
    float* tsc    = ws + 14870944;
    int*   tidx   = (int*)(ws + 14918944);
    float* Wt     = ws + 14966944;

    w1pack_kernel<<<512, 256, 0, stream>>>(W1, W1pack);
    wtpack_kernel<<<108, 256, 0, stream>>>(Wreg, Wcls, Wt);
    conv_mfma_kernel<<<dim3(20, 4, 8), 256, 0, stream>>>(feat, (const char*)W1pack, b1, conv1);
    heads_kernel<<<1250, 256, 0, stream>>>(conv1, Wt, breg, bcls, boxes, scores);
    topk_kernel<<<8, 1024, 0, stream>>>(scores, boxes, tsc, tbx, tidx);
    rank_kernel<<<dim3(24, 8), 256, 0, stream>>>(tsc, tidx, tbx, sbx, ssc);
    mask_kernel<<<dim3(94, 8), 256, 0, stream>>>(sbx, mask);
    nmsbit_kernel<<<8, 64, 0, stream>>>(ssc, sbx, mask, out);
  }
}

// Round 18
// 1216.906 us; speedup vs baseline: 1.2773x; 1.0824x over previous
//
#include <hip/hip_runtime.h>
#include <hip/hip_bf16.h>
#include <math.h>

#define NEGV -1e9f
#define NEGH -5e8f

typedef __attribute__((ext_vector_type(8))) short short8;
typedef __attribute__((ext_vector_type(4))) float f32x4;

__device__ __forceinline__ unsigned fkey(float f) {
  unsigned u = __float_as_uint(f);
  return (u & 0x80000000u) ? ~u : (u | 0x80000000u);
}
__device__ __forceinline__ unsigned long long key48(float s, int j) {
  return ((unsigned long long)fkey(s) << 15) | (unsigned long long)(32767 - j);
}
__device__ __forceinline__ unsigned short bf16_rne(float v) {
  unsigned u = __float_as_uint(v);
  unsigned r = u + 0x7FFFu + ((u >> 16) & 1u);
  return (unsigned short)(r >> 16);
}
__device__ __forceinline__ float bf16_f(unsigned short h) {
  return __uint_as_float(((unsigned)h) << 16);
}

#if defined(__has_builtin)
#if __has_builtin(__builtin_amdgcn_global_load_lds)
#define HAS_GLL 1
#endif
#endif

__device__ __forceinline__ void stage16(const char* gsrc_lane, char* ldsbase, int ln) {
#ifdef HAS_GLL
  typedef unsigned int __attribute__((address_space(1))) gu32;
  typedef unsigned int __attribute__((address_space(3))) lu32;
  __builtin_amdgcn_global_load_lds((const gu32*)gsrc_lane, (lu32*)ldsbase, 16, 0, 0);
#else
  *(uint4*)(ldsbase + ln * 16) = *(const uint4*)gsrc_lane;
#endif
}

// ==================================================================
// K-order: TAP-MAJOR — FROZEN. conv1 bitwise = r5-r17 lineage.
// r18: feat split-3 PRECOMPUTED into dword planes (same bf16_rne
// chain -> same LDS bytes -> bitwise-identical conv1); ws-gated with
// verbatim-r17 fallback.
// ==================================================================

// ------------------------------------------------------------------
// Pack W1 (coalesced, verbatim r12-r17)
// ------------------------------------------------------------------
__global__ __launch_bounds__(256) void w1pack_kernel(
    const float* __restrict__ W1, unsigned* __restrict__ W1pack) {
  int g = blockIdx.x * 256 + threadIdx.x;   // 512*256 = 131072 exact
  int oc = g >> 8;
  int cp = g & 255;
  int cin = cp * 2;
  int ct = oc >> 7;
  int row = oc & 127;
  float buf[18];
  const float* src = W1 + (size_t)oc * 4608 + cin * 9;
  #pragma unroll
  for (int i = 0; i < 18; ++i) buf[i] = src[i];
  int k = cin & 31;
  int R = row >> 1;
  int val = ((row & 1) << 6) | (k << 1);
  int tb = (R << 7) | (val ^ ((R & 7) << 4));
  int dwimg = tb >> 2;
  int sBase = cp >> 4;
  #pragma unroll
  for (int tap = 0; tap < 9; ++tap) {
    float w0 = buf[tap], w1 = buf[9 + tap];
    unsigned short h0 = bf16_rne(w0), h1 = bf16_rne(w1);
    float r0 = w0 - bf16_f(h0), r1 = w1 - bf16_f(h1);
    unsigned short m0 = bf16_rne(r0), m1 = bf16_rne(r1);
    unsigned short l0 = bf16_rne(r0 - bf16_f(m0)), l1 = bf16_rne(r1 - bf16_f(m1));
    int s = tap * 16 + sBase;               // tap-major (frozen)
    size_t base = ((size_t)(ct * 144 + s) * 3) * 2048 + dwimg;
    W1pack[base]        = (unsigned)h0 | ((unsigned)h1 << 16);
    W1pack[base + 2048] = (unsigned)m0 | ((unsigned)m1 << 16);
    W1pack[base + 4096] = (unsigned)l0 | ((unsigned)l1 << 16);
  }
}

// ------------------------------------------------------------------
// Feat split-3 precompute: featH/M/L[b][cinpair][pix] = lo|hi<<16,
// identical bf16_rne chain as in-kernel writeB (bitwise-safe).
// ------------------------------------------------------------------
__global__ __launch_bounds__(256) void fsplit_kernel(
    const float* __restrict__ feat, unsigned* __restrict__ featH,
    unsigned* __restrict__ featM, unsigned* __restrict__ featL) {
  int g = blockIdx.x * 256 + threadIdx.x;   // 20000*256 = 5,120,000 exact
  int pix = g % 2500;
  int rest = g / 2500;                       // b*256 + cp
  const float* fb = feat + (size_t)rest * 2 * 2500 + pix;
  float v0 = fb[0];
  float v1 = fb[2500];
  unsigned short h0 = bf16_rne(v0), h1 = bf16_rne(v1);
  float r0 = v0 - bf16_f(h0), r1 = v1 - bf16_f(h1);
  unsigned short m0 = bf16_rne(r0), m1 = bf16_rne(r1);
  unsigned short l0 = bf16_rne(r0 - bf16_f(m0)), l1 = bf16_rne(r1 - bf16_f(m1));
  featH[g] = (unsigned)h0 | ((unsigned)h1 << 16);
  featM[g] = (unsigned)m0 | ((unsigned)m1 << 16);
  featL[g] = (unsigned)l0 | ((unsigned)l1 << 16);
}

// ------------------------------------------------------------------
// Heads weight transpose v2 (verbatim r16/17)
// ------------------------------------------------------------------
__global__ __launch_bounds__(256) void wtpack_kernel(
    const float* __restrict__ Wreg, const float* __restrict__ Wcls,
    float* __restrict__ Wt) {
  int i = blockIdx.x * 256 + threadIdx.x;   // 108*256 = 27648 exact
  int gg = i / 216;
  int r  = i - gg * 216;
  int j  = r >> 2;
  int c  = gg * 4 + (r & 3);
  Wt[i] = (j < 36) ? Wreg[j * 512 + c] : Wcls[(j - 36) * 512 + c];
}

// ------------------------------------------------------------------
// Conv (pre-split B): identical structure/barriers/LDS bytes to the
// frozen kernel; writeB is now pure data movement (zero split VALU).
// ------------------------------------------------------------------
__global__ __launch_bounds__(256) void conv_mfma_pre_kernel(
    const unsigned* __restrict__ featH, const unsigned* __restrict__ featM,
    const unsigned* __restrict__ featL, const char* __restrict__ W1pack,
    const float* __restrict__ b1, float* __restrict__ conv1) {
  __shared__ char smem[49152];
  const int tid = threadIdx.x;
  const int b  = blockIdx.z;
  const int ct = blockIdx.y;
  const int n0 = blockIdx.x * 128;
  const int wv = tid >> 6, ln = tid & 63;

  const int spix = tid & 127;
  const int kh   = tid >> 7;
  int p = n0 + spix; if (p > 2499) p = 2499;
  const int pyy = p / 50;
  const int pxx = p - pyy * 50;
  const unsigned* fhb = featH + (size_t)b * 256 * 2500;
  const unsigned* fmb = featM + (size_t)b * 256 * 2500;
  const unsigned* flb = featL + (size_t)b * 256 * 2500;
  const char* wsrc = W1pack + (size_t)ct * 144 * 24576;

  const int wch0  = (wv >> 1) * 64;
  const int wpix0 = (wv & 1) * 64;
  const int lrow = ln & 15, lg = ln >> 4;

  f32x4 acc[4][4];
  #pragma unroll
  for (int i = 0; i < 4; ++i)
    #pragma unroll
    for (int j = 0; j < 4; ++j) acc[i][j] = (f32x4)0.f;

  unsigned uh[8], um[8], ul[8];

  auto loadFeat = [&](int s) {
    int tap = s >> 4;
    int dy = tap / 3, dx = tap - dy * 3;
    int iy = pyy + dy - 1, ix = pxx + dx - 1;
    bool ok = ((unsigned)iy < 50u) && ((unsigned)ix < 50u);
    int cpb = ((s & 15) << 4) + kh * 8;     // cinpair base
    size_t off = (size_t)cpb * 2500 + iy * 50 + ix;
    #pragma unroll
    for (int i = 0; i < 8; ++i) {
      size_t o = off + (size_t)i * 2500;
      uh[i] = ok ? fhb[o] : 0u;
      um[i] = ok ? fmb[o] : 0u;
      ul[i] = ok ? flb[o] : 0u;
    }
  };
  auto issueA = [&](int s) {
    const char* src = wsrc + (size_t)s * 24576;
    char* lbase = smem + (tid >> 6) * 1024;
    #pragma unroll
    for (int c = 0; c < 6; ++c)
      stage16(src + c * 4096 + tid * 16, lbase + c * 4096, ln);
  };
  auto writeB = [&]() {
    const int r = spix >> 1;
    const int swz = (r & 7) << 4;
    char* rowb = smem + 24576 + r * 128;
    #pragma unroll
    for (int pl = 0; pl < 3; ++pl) {
      const unsigned* sp = (pl == 0) ? uh : (pl == 1 ? um : ul);
      char* pb = rowb + pl * 8192;
      #pragma unroll
      for (int q = 0; q < 4; ++q) {
        int pre = ((spix & 1) << 6) + kh * 32 + q * 8;
        uint2 w;
        w.x = sp[2 * q];
        w.y = sp[2 * q + 1];
        *(uint2*)(pb + (pre ^ swz)) = w;
      }
    }
  };
  auto rdFrag = [&](const char* base, int row) -> short8 {
    int byte = (row >> 1) * 128 +
               ((((row & 1) << 6) + (lg << 4)) ^ (((row >> 1) & 7) << 4));
    return *(const short8*)(base + byte);
  };

  loadFeat(0);
  #pragma unroll 1
  for (int s = 0; s < 144; ++s) {
    __syncthreads();
    issueA(s);
    writeB();
    __syncthreads();
    if (s + 1 < 144) loadFeat(s + 1);
    short8 fa[3][4];
    #pragma unroll
    for (int pl = 0; pl < 3; ++pl)
      #pragma unroll
      for (int f = 0; f < 4; ++f)
        fa[pl][f] = rdFrag(smem + pl * 8192, wch0 + f * 16 + lrow);
    #pragma unroll
    for (int jb = 0; jb < 3; ++jb) {
      short8 fb[4];
      #pragma unroll
      for (int f = 0; f < 4; ++f)
        fb[f] = rdFrag(smem + 24576 + jb * 8192, wpix0 + f * 16 + lrow);
      const int na = 3 - jb;
      #pragma unroll
      for (int ap = 0; ap < 3; ++ap) {
        if (ap < na) {
          #pragma unroll
          for (int i = 0; i < 4; ++i)
            #pragma unroll
            for (int j = 0; j < 4; ++j)
              acc[i][j] = __builtin_amdgcn_mfma_f32_16x16x32_bf16(
                  fa[ap][i], fb[j], acc[i][j], 0, 0, 0);
        }
      }
    }
  }

  const int chb = ct * 128 + wch0 + lg * 4;
  #pragma unroll
  for (int i = 0; i < 4; ++i) {
    int ch = chb + i * 16;
    float4 bias = *(const float4*)&b1[ch];
    #pragma unroll
    for (int j = 0; j < 4; ++j) {
      int pix = n0 + wpix0 + j * 16 + lrow;
      if (pix < 2500) {
        float4 o;
        o.x = fmaxf(acc[i][j][0] + bias.x, 0.f);
        o.y = fmaxf(acc[i][j][1] + bias.y, 0.f);
        o.z = fmaxf(acc[i][j][2] + bias.z, 0.f);
        o.w = fmaxf(acc[i][j][3] + bias.w, 0.f);
        *(float4*)&conv1[(size_t)(b * 2500 + pix) * 512 + ch] = o;
      }
    }
  }
}

// ------------------------------------------------------------------
// Conv (verbatim r17 FROZEN text) — fallback for smaller workspace.
// ------------------------------------------------------------------
__global__ __launch_bounds__(256) void conv_mfma_kernel(
    const float* __restrict__ feat, const char* __restrict__ W1pack,
    const float* __restrict__ b1, float* __restrict__ conv1) {
  __shared__ char smem[49152];
  const int tid = threadIdx.x;
  const int b  = blockIdx.z;
  const int ct = blockIdx.y;
  const int n0 = blockIdx.x * 128;
  const int wv = tid >> 6, ln = tid & 63;

  const int spix = tid & 127;
  const int kh   = tid >> 7;
  int p = n0 + spix; if (p > 2499) p = 2499;
  const int pyy = p / 50;
  const int pxx = p - pyy * 50;
  const float* featb = feat + (size_t)b * 512 * 2500;
  const char* wsrc = W1pack + (size_t)ct * 144 * 24576;

  const int wch0  = (wv >> 1) * 64;
  const int wpix0 = (wv & 1) * 64;
  const int lrow = ln & 15, lg = ln >> 4;

  f32x4 acc[4][4];
  #pragma unroll
  for (int i = 0; i < 4; ++i)
    #pragma unroll
    for (int j = 0; j < 4; ++j) acc[i][j] = (f32x4)0.f;

  float u[16];

  auto loadFeat = [&](int s) {
    int tap = s >> 4;
    int dy = tap / 3, dx = tap - dy * 3;
    int iy = pyy + dy - 1, ix = pxx + dx - 1;
    bool ok = ((unsigned)iy < 50u) && ((unsigned)ix < 50u);
    int cinb = ((s & 15) << 5) + kh * 16;
    const float* base = featb + (size_t)cinb * 2500 + iy * 50 + ix;
    #pragma unroll
    for (int i = 0; i < 16; ++i) u[i] = ok ? base[(size_t)i * 2500] : 0.f;
  };
  auto issueA = [&](int s) {
    const char* src = wsrc + (size_t)s * 24576;
    char* lbase = smem + (tid >> 6) * 1024;
    #pragma unroll
    for (int c = 0; c < 6; ++c)
      stage16(src + c * 4096 + tid * 16, lbase + c * 4096, ln);
  };
  auto writeB = [&]() {
    unsigned short h[16], m[16], l[16];
    #pragma unroll
    for (int i = 0; i < 16; ++i) {
      float v = u[i];
      h[i] = bf16_rne(v);
      float r1 = v - bf16_f(h[i]);
      m[i] = bf16_rne(r1);
      float r2 = r1 - bf16_f(m[i]);
      l[i] = bf16_rne(r2);
    }
    const int r = spix >> 1;
    const int swz = (r & 7) << 4;
    char* rowb = smem + 24576 + r * 128;
    #pragma unroll
    for (int pl = 0; pl < 3; ++pl) {
      const unsigned short* sp = (pl == 0) ? h : (pl == 1 ? m : l);
      char* pb = rowb + pl * 8192;
      #pragma unroll
      for (int q = 0; q < 4; ++q) {
        int pre = ((spix & 1) << 6) + kh * 32 + q * 8;
        uint2 w;
        w.x = (unsigned)sp[q*4]   | ((unsigned)sp[q*4+1] << 16);
        w.y = (unsigned)sp[q*4+2] | ((unsigned)sp[q*4+3] << 16);
        *(uint2*)(pb + (pre ^ swz)) = w;
      }
    }
  };
  auto rdFrag = [&](const char* base, int row) -> short8 {
    int byte = (row >> 1) * 128 +
               ((((row & 1) << 6) + (lg << 4)) ^ (((row >> 1) & 7) << 4));
    return *(const short8*)(base + byte);
  };

  loadFeat(0);
  #pragma unroll 1
  for (int s = 0; s < 144; ++s) {
    __syncthreads();
    issueA(s);
    writeB();
    __syncthreads();
    if (s + 1 < 144) loadFeat(s + 1);
    short8 fa[3][4];
    #pragma unroll
    for (int pl = 0; pl < 3; ++pl)
      #pragma unroll
      for (int f = 0; f < 4; ++f)
        fa[pl][f] = rdFrag(smem + pl * 8192, wch0 + f * 16 + lrow);
    #pragma unroll
    for (int jb = 0; jb < 3; ++jb) {
      short8 fb[4];
      #pragma unroll
      for (int f = 0; f < 4; ++f)
        fb[f] = rdFrag(smem + 24576 + jb * 8192, wpix0 + f * 16 + lrow);
      const int na = 3 - jb;
      #pragma unroll
      for (int ap = 0; ap < 3; ++ap) {
        if (ap < na) {
          #pragma unroll
          for (int i = 0; i < 4; ++i)
            #pragma unroll
            for (int j = 0; j < 4; ++j)
              acc[i][j] = __builtin_amdgcn_mfma_f32_16x16x32_bf16(
                  fa[ap][i], fb[j], acc[i][j], 0, 0, 0);
        }
      }
    }
  }

  const int chb = ct * 128 + wch0 + lg * 4;
  #pragma unroll
  for (int i = 0; i < 4; ++i) {
    int ch = chb + i * 16;
    float4 bias = *(const float4*)&b1[ch];
    #pragma unroll
    for (int j = 0; j < 4; ++j) {
      int pix = n0 + wpix0 + j * 16 + lrow;
      if (pix < 2500) {
        float4 o;
        o.x = fmaxf(acc[i][j][0] + bias.x, 0.f);
        o.y = fmaxf(acc[i][j][1] + bias.y, 0.f);
        o.z = fmaxf(acc[i][j][2] + bias.z, 0.f);
        o.w = fmaxf(acc[i][j][3] + bias.w, 0.f);
        *(float4*)&conv1[(size_t)(b * 2500 + pix) * 512 + ch] = o;
      }
    }
  }
}

// ------------------------------------------------------------------
// Heads v3 (verbatim r16/17, verified)
// ------------------------------------------------------------------
__global__ __launch_bounds__(256) void heads_kernel(
    const float* __restrict__ conv1, const float* __restrict__ Wt,
    const float* __restrict__ breg, const float* __restrict__ bcls,
    float* __restrict__ boxes, float* __restrict__ scores) {
  __shared__ float v[16][512];
  __shared__ float o54[16][56];
  const int tid = threadIdx.x;
  const int wvi = tid >> 6, lane = tid & 63;
  const int pix0 = blockIdx.x * 16;
  float4* vf = (float4*)v;
  const float4* src4 = (const float4*)(conv1 + (size_t)pix0 * 512);
  #pragma unroll
  for (int i = 0; i < 8; ++i) vf[i * 256 + tid] = src4[i * 256 + tid];
  __syncthreads();

  if (lane < 54) {
    float s[4][4];
    #pragma unroll
    for (int p = 0; p < 4; ++p)
      #pragma unroll
      for (int q = 0; q < 4; ++q) s[p][q] = 0.f;
    const int pl0 = wvi * 4;
    for (int c = 0; c < 512; c += 4) {
      float4 w = *(const float4*)&Wt[(c >> 2) * 216 + lane * 4];
      #pragma unroll
      for (int p = 0; p < 4; ++p) {
        s[p][0] = fmaf(v[pl0 + p][c],     w.x, s[p][0]);
        s[p][1] = fmaf(v[pl0 + p][c + 1], w.y, s[p][1]);
        s[p][2] = fmaf(v[pl0 + p][c + 2], w.z, s[p][2]);
        s[p][3] = fmaf(v[pl0 + p][c + 3], w.w, s[p][3]);
      }
    }
    float bias = (lane < 36) ? breg[lane] : bcls[lane - 36];
    #pragma unroll
    for (int p = 0; p < 4; ++p)
      o54[pl0 + p][lane] = (s[p][0] + s[p][1]) + (s[p][2] + s[p][3]) + bias;
  }
  __syncthreads();

  if (tid < 144) {
    const int pl = tid / 9;
    const int a  = tid - pl * 9;
    const int pix = pix0 + pl;
    const int b = pix / 2500;
    const int n = pix - b * 2500;
    const int y = n / 50, x = n - y * 50;
    float d0 = o54[pl][a * 4 + 0], d1 = o54[pl][a * 4 + 1];
    float d2 = o54[pl][a * 4 + 2], d3 = o54[pl][a * 4 + 3];
    float sc0 = o54[pl][36 + a * 2], sc1 = o54[pl][36 + a * 2 + 1];
    float mx = fmaxf(sc0, sc1);
    float e0 = expf(sc0 - mx), e1 = expf(sc1 - mx);
    float fg = e1 / (e0 + e1);
    const int ri = a / 3;
    const int si = a - ri * 3;
    float sv = (si == 0) ? 8.f : (si == 1 ? 16.f : 32.f);
    float sqr_r  = (ri == 0) ? 0.70710678f : (ri == 1 ? 1.f : 1.41421356f);
    float sqr_ir = (ri == 0) ? 1.41421356f : (ri == 1 ? 1.f : 0.70710678f);
    float hh = 16.f * sv * sqr_r;
    float ww = 16.f * sv * sqr_ir;
    float acy = 16.f * (float)(y + 1) - 25.f;
    float acx = 16.f * (float)(x + 1) - 25.f;
    float ay1 = acy - 0.5f * hh, ay2 = acy + 0.5f * hh;
    float ax1 = acx - 0.5f * ww, ax2 = acx + 0.5f * ww;
    float ah = ay2 - ay1, aw = ax2 - ax1;
    float cy0 = ay1 + 0.5f * ah, cx0 = ax1 + 0.5f * aw;
    float cy = d0 * ah + cy0, cx = d1 * aw + cx0;
    float bh = expf(d2) * ah, bw = expf(d3) * aw;
    float y1 = cy - 0.5f * bh, x1 = cx - 0.5f * bw;
    float y2 = cy + 0.5f * bh, x2 = cx + 0.5f * bw;
    y1 = fminf(fmaxf(y1, 0.f), 800.f); y2 = fminf(fmaxf(y2, 0.f), 800.f);
    x1 = fminf(fmaxf(x1, 0.f), 800.f); x2 = fminf(fmaxf(x2, 0.f), 800.f);
    bool ok = ((y2 - y1) >= 16.f) && ((x2 - x1) >= 16.f);
    int gi = b * 22500 + n * 9 + a;
    ((float4*)boxes)[gi] = make_float4(y1, x1, y2, x2);
    scores[gi] = (ok && fg == fg) ? fg : NEGV;
  }
}

// ------------------------------------------------------------------
// Top-6000 radix select — per-wave histograms (verbatim r15-17)
// ------------------------------------------------------------------
__global__ __launch_bounds__(1024) void topk_kernel(
    const float* __restrict__ scores, const float* __restrict__ boxes,
    float* __restrict__ tsc, float* __restrict__ tbx, int* __restrict__ tidx) {
  const int b = blockIdx.x, tid = threadIdx.x;
  __shared__ unsigned hist[16][256];
  __shared__ unsigned long long sh_pref;
  __shared__ unsigned sh_rem, sh_cnt;
  const int wid = tid >> 6;
  const float* sc = scores + b * 22500;
  if (tid == 0) { sh_pref = 0ull; sh_rem = 6000u; }
  __syncthreads();
  for (int pass = 0; pass < 6; ++pass) {
    const int shift = 40 - pass * 8;
    #pragma unroll
    for (int i = tid; i < 4096; i += 1024) ((unsigned*)hist)[i] = 0u;
    __syncthreads();
    const unsigned long long pref = sh_pref;
    for (int j = tid; j < 22500; j += 1024) {
      unsigned long long key = key48(sc[j], j);
      if ((key >> (shift + 8)) == pref)
        atomicAdd(&hist[wid][(unsigned)(key >> shift) & 255u], 1u);
    }
    __syncthreads();
    if (tid < 256) {
      unsigned s = 0;
      #pragma unroll
      for (int w = 0; w < 16; ++w) s += hist[w][tid];
      hist[0][tid] = s;
    }
    __syncthreads();
    if (tid == 0) {
      unsigned rem = sh_rem;
      unsigned c = 0; int sel = 0;
      for (int bin = 255; bin >= 0; --bin) {
        unsigned nc = c + hist[0][bin];
        if (nc >= rem) { sel = bin; break; }
        c = nc;
      }
      sh_rem = rem - c;
      sh_pref = (sh_pref << 8) | (unsigned long long)sel;
    }
    __syncthreads();
  }
  const unsigned long long T = sh_pref;
  if (tid == 0) sh_cnt = 0u;
  __syncthreads();
  const float4* bx4 = (const float4*)boxes;
  float4* tb4 = (float4*)tbx;
  for (int j = tid; j < 22500; j += 1024) {
    unsigned long long key = key48(sc[j], j);
    if (key >= T) {
      unsigned slot = atomicAdd(&sh_cnt, 1u);
      if (slot < 6000u) {
        tsc[b * 6000 + slot] = sc[j];
        tidx[b * 6000 + slot] = j;
        tb4[b * 6000 + slot] = bx4[b * 22500 + j];
      }
    }
  }
}

// ------------------------------------------------------------------
// Rank-sort v2 (verbatim r16/17, verified)
// ------------------------------------------------------------------
__global__ __launch_bounds__(256) void rank_kernel(
    const float* __restrict__ tsc, const int* __restrict__ tidx,
    const float* __restrict__ tbx,
    float* __restrict__ sbx, float* __restrict__ ssc) {
  __shared__ unsigned long long keys[6000];
  const int b = blockIdx.y;
  const int tid = threadIdx.x;
  const int c = blockIdx.x * 256 + tid;
  const float* scb = tsc + b * 6000;
  const int* idb = tidx + b * 6000;
  for (int j = tid; j < 6000; j += 256)
    keys[j] = key48(scb[j], idb[j]);
  __syncthreads();
  unsigned long long kc = (c < 6000) ? keys[c] : ~0ull;
  int rank = 0;
  #pragma unroll 4
  for (int j = 0; j < 6000; ++j)
    rank += (keys[j] > kc) ? 1 : 0;
  if (c < 6000) {
    ((float4*)sbx)[b * 6000 + rank] = ((const float4*)tbx)[b * 6000 + c];
    ssc[b * 6000 + rank] = scb[c];
  }
}

// ------------------------------------------------------------------
// Suppression bitmask — TRIANGLE (verbatim r17, verified)
// ------------------------------------------------------------------
__global__ __launch_bounds__(256) void mask_kernel(
    const float* __restrict__ sbx, unsigned long long* __restrict__ mask) {
  const int b = blockIdx.y;
  const int c0 = blockIdx.x;
  const int row = c0 * 64 + (threadIdx.x & 63);
  const int wseg = threadIdx.x >> 6;
  __shared__ float4 jb[512];
  const float4* sb4 = (const float4*)sbx + (size_t)b * 6000;
  float4 rb = sb4[row < 6000 ? row : 5999];
  const float ra = (rb.z - rb.x) * (rb.w - rb.y);
  unsigned long long m[24];
  #pragma unroll
  for (int q = 0; q < 24; ++q) m[q] = 0ull;
  const int jt0 = c0 >> 3;
  for (int jt = jt0; jt < 12; ++jt) {
    __syncthreads();
    for (int s = threadIdx.x; s < 512; s += 256) {
      int j = jt * 512 + s;
      jb[s] = (j < 6000) ? sb4[j] : make_float4(0.f, 0.f, 0.f, 0.f);
    }
    __syncthreads();
    #pragma unroll
    for (int ww = 0; ww < 2; ++ww) {
      int w = jt * 8 + wseg * 2 + ww;
      if (w >= 94 || w < c0) continue;
      int j0 = (wseg * 2 + ww) * 64;
      unsigned long long bits = 0ull;
      #pragma unroll
      for (int u = 0; u < 64; ++u) {
        float4 bb = jb[j0 + u];
        float aj = (bb.z - bb.x) * (bb.w - bb.y);
        float yy1 = fmaxf(rb.x, bb.x), xx1 = fmaxf(rb.y, bb.y);
        float yy2 = fminf(rb.z, bb.z), xx2 = fminf(rb.w, bb.w);
        float inter = fmaxf(yy2 - yy1, 0.f) * fmaxf(xx2 - xx1, 0.f);
        float iou = inter / (((ra + aj) - inter) + 1e-9f);
        bits |= (iou > 0.7f) ? (1ull << u) : 0ull;
      }
      m[jt * 2 + ww] = bits;
    }
  }
  if (row < 6000) {
    unsigned long long* mr = mask + (size_t)(b * 6000 + row) * 94;
    #pragma unroll
    for (int jt = 0; jt < 12; ++jt)
      #pragma unroll
      for (int ww = 0; ww < 2; ++ww) {
        int w = jt * 8 + wseg * 2 + ww;
        if (w < 94 && w >= c0) mr[w] = m[jt * 2 + ww];
      }
  }
}

// ------------------------------------------------------------------
// Greedy bitmask walk (verbatim r17, verified)
// ------------------------------------------------------------------
__global__ __launch_bounds__(64) void nmsbit_kernel(
    const float* __restrict__ ssc, const float* __restrict__ sbx,
    const unsigned long long* __restrict__ mask, float* __restrict__ out) {
  const int b = blockIdx.x, lane = threadIdx.x;
  __shared__ unsigned long long live[94];
  __shared__ int picks[300];
  const unsigned long long* mbase = mask + (size_t)b * 6000 * 94;
  int cnt = 0;
  for (int j = lane; j < 6000; j += 64)
    cnt += (ssc[b * 6000 + j] > NEGH) ? 1 : 0;
  #pragma unroll
  for (int off = 32; off > 0; off >>= 1) cnt += __shfl_down(cnt, off);
  const int nvalid = __shfl(cnt, 0);
  for (int w = lane; w < 94; w += 64) {
    int base = w * 64;
    unsigned long long mm;
    if (base + 64 <= nvalid) mm = ~0ull;
    else if (base >= nvalid) mm = 0ull;
    else mm = (~0ull) >> (64 - (nvalid - base));
    live[w] = mm;
  }
  __syncthreads();

  int np = 0;
  for (int c = 0; c < 94 && np < 300; ++c) {
    unsigned long long bits = live[c];
    if (bits == 0ull) continue;
    int row = c * 64 + lane;
    unsigned long long dw = (row < 6000) ? mbase[(size_t)row * 94 + c] : 0ull;
    unsigned long long prows = 0ull;
    while (bits != 0ull && np < 300) {
      int bpos = __ffsll(bits) - 1;
      if (lane == 0) picks[np] = c * 64 + bpos;
      np++;
      prows |= (1ull << bpos);
      unsigned long long dwb = __shfl(dw, bpos);
      bits &= ~dwb;
      bits &= ~(1ull << bpos);
    }
    const bool g0 = (lane >= c);
    const bool g1 = (lane < 30) && (lane + 64 >= c);
    unsigned long long acc0 = 0ull, acc1 = 0ull;
    unsigned long long pr = prows;
    while (pr != 0ull) {
      int r0, r1 = -1, r2 = -1, r3 = -1;
      r0 = __ffsll(pr) - 1; pr &= pr - 1ull;
      if (pr) { r1 = __ffsll(pr) - 1; pr &= pr - 1ull; }
      if (r1 >= 0 && pr) { r2 = __ffsll(pr) - 1; pr &= pr - 1ull; }
      if (r2 >= 0 && pr) { r3 = __ffsll(pr) - 1; pr &= pr - 1ull; }
      const unsigned long long* q0 = mbase + (size_t)(c * 64 + r0) * 94;
      unsigned long long a0 = g0 ? q0[lane] : 0ull;
      unsigned long long a1 = g1 ? q0[lane + 64] : 0ull;
      unsigned long long b0 = 0ull, b1 = 0ull, c0_ = 0ull, c1 = 0ull,
                         d0 = 0ull, d1 = 0ull;
      if (r1 >= 0) {
        const unsigned long long* q = mbase + (size_t)(c * 64 + r1) * 94;
        b0 = g0 ? q[lane] : 0ull; b1 = g1 ? q[lane + 64] : 0ull;
      }
      if (r2 >= 0) {
        const unsigned long long* q = mbase + (size_t)(c * 64 + r2) * 94;
        c0_ = g0 ? q[lane] : 0ull; c1 = g1 ? q[lane + 64] : 0ull;
      }
      if (r3 >= 0) {
        const unsigned long long* q = mbase + (size_t)(c * 64 + r3) * 94;
        d0 = g0 ? q[lane] : 0ull; d1 = g1 ? q[lane + 64] : 0ull;
      }
      acc0 |= (a0 | b0) | (c0_ | d0);
      acc1 |= (a1 | b1) | (c1 | d1);
    }
    if (prows != 0ull) {
      live[lane] &= ~acc0;
      if (lane < 30) live[lane + 64] &= ~acc1;
      __syncthreads();
    }
  }
  __syncthreads();

  float* rois = out;
  float* rsc  = out + 12000;
  for (int t = lane; t < 300; t += 64) {
    float* rp = rois + (size_t)(b * 300 + t) * 5;
    if (t < np) {
      int i = picks[t];
      float4 bb = ((const float4*)sbx)[b * 6000 + i];
      rp[0] = (float)b; rp[1] = bb.x; rp[2] = bb.y; rp[3] = bb.z; rp[4] = bb.w;
      rsc[b * 300 + t] = ssc[b * 6000 + i];
    } else {
      rp[0] = 0.f; rp[1] = 0.f; rp[2] = 0.f; rp[3] = 0.f; rp[4] = 0.f;
      rsc[b * 300 + t] = 0.f;
    }
  }
}

// ------------------------------------------------------------------
extern "C" void kernel_launch(void* const* d_in, const int* in_sizes, int n_in,
                              void* d_out, int out_size, void* d_ws, size_t ws_size,
                              hipStream_t stream) {
  const float* feat = (const float*)d_in[0];
  const float* W1   = (const float*)d_in[1];
  const float* b1   = (const float*)d_in[2];
  const float* Wreg = (const float*)d_in[3];
  const float* breg = (const float*)d_in[4];
  const float* Wcls = (const float*)d_in[5];
  const float* bcls = (const float*)d_in[6];
  float* out = (float*)d_out;
  float* ws  = (float*)d_ws;

  const size_t NEED2 = 121418368ull;   // pre-split path
  const size_t NEED  = 59978368ull;    // r17 path (proven available)
  if (ws_size >= NEED2) {
    unsigned* W1pack = (unsigned*)ws;                  //  3,538,944 f
    unsigned* featH  = (unsigned*)(ws + 3538944);      //  5,120,000
    unsigned* featM  = (unsigned*)(ws + 8658944);      //  5,120,000
    unsigned* featL  = (unsigned*)(ws + 13778944);     //  5,120,000
    float* conv1  = ws + 18898944;                     // 10,240,000
    unsigned long long* mask = (unsigned long long*)(ws + 18898944); // alias conv1
    float* boxes  = ws + 29138944;
    float* sbx    = ws + 29138944;                     // alias boxes
    float* ssc    = ws + 29330944;
    float* scores = ws + 29858944;
    float* tbx    = ws + 30038944;
    float* tsc    = ws + 30230944;
    int*   tidx   = (int*)(ws + 30278944);
    float* Wt     = ws + 30326944;

    w1pack_kernel<<<512, 256, 0, stream>>>(W1, W1pack);
    fsplit_kernel<<<20000, 256, 0, stream>>>(feat, featH, featM, featL);
    wtpack_kernel<<<108, 256, 0, stream>>>(Wreg, Wcls, Wt);
    conv_mfma_pre_kernel<<<dim3(20, 4, 8), 256, 0, stream>>>(
        featH, featM, featL, (const char*)W1pack, b1, conv1);
    heads_kernel<<<1250, 256, 0, stream>>>(conv1, Wt, breg, bcls, boxes, scores);
    topk_kernel<<<8, 1024, 0, stream>>>(scores, boxes, tsc, tbx, tidx);
    rank_kernel<<<dim3(24, 8), 256, 0, stream>>>(tsc, tidx, tbx, sbx, ssc);
    mask_kernel<<<dim3(94, 8), 256, 0, stream>>>(sbx, mask);
    nmsbit_kernel<<<8, 64, 0, stream>>>(ssc, sbx, mask, out);
  } else if (ws_size >= NEED) {
    // verbatim r17 configuration
    unsigned* W1pack = (unsigned*)ws;
    float* conv1  = ws + 3538944;
    unsigned long long* mask = (unsigned long long*)(ws + 3538944);
    float* boxes  = ws + 13778944;
    float* sbx    = ws + 13778944;
    float* ssc    = ws + 13970944;
    float* scores = ws + 14498944;
    float* tbx    = ws + 14678944;
    float* tsc    = ws + 14870944;
    int*   tidx   = (int*)(ws + 14918944);
    float* Wt     = ws + 14966944;

    w1pack_kernel<<<512, 256, 0, stream>>>(W1, W1pack);
    wtpack_kernel<<<108, 256, 0, stream>>>(Wreg, Wcls, Wt);
    conv_mfma_kernel<<<dim3(20, 4, 8), 256, 0, stream>>>(feat, (const char*)W1pack, b1, conv1);
    heads_kernel<<<1250, 256, 0, stream>>>(conv1, Wt, breg, bcls, boxes, scores);
    topk_kernel<<<8, 1024, 0, stream>>>(scores, boxes, tsc, tbx, tidx);
    rank_kernel<<<dim3(24, 8), 256, 0, stream>>>(tsc, tidx, tbx, sbx, ssc);
    mask_kernel<<<dim3(94, 8), 256, 0, stream>>>(sbx, mask);
    nmsbit_kernel<<<8, 64, 0, stream>>>(ssc, sbx, mask, out);
  }
}

// Round 19
// 1195.804 us; speedup vs baseline: 1.2998x; 1.0176x over previous
//
#include <hip/hip_runtime.h>
#include <hip/hip_bf16.h>
#include <math.h>

#define NEGV -1e9f
#define NEGH -5e8f

typedef __attribute__((ext_vector_type(8))) short short8;
typedef __attribute__((ext_vector_type(4))) float f32x4;

__device__ __forceinline__ unsigned fkey(float f) {
  unsigned u = __float_as_uint(f);
  return (u & 0x80000000u) ? ~u : (u | 0x80000000u);
}
__device__ __forceinline__ unsigned long long key48(float s, int j) {
  return ((unsigned long long)fkey(s) << 15) | (unsigned long long)(32767 - j);
}
__device__ __forceinline__ unsigned short bf16_rne(float v) {
  unsigned u = __float_as_uint(v);
  unsigned r = u + 0x7FFFu + ((u >> 16) & 1u);
  return (unsigned short)(r >> 16);
}
__device__ __forceinline__ float bf16_f(unsigned short h) {
  return __uint_as_float(((unsigned)h) << 16);
}

#if defined(__has_builtin)
#if __has_builtin(__builtin_amdgcn_global_load_lds)
#define HAS_GLL 1
#endif
#endif

__device__ __forceinline__ void stage16(const char* gsrc_lane, char* ldsbase, int ln) {
#ifdef HAS_GLL
  typedef unsigned int __attribute__((address_space(1))) gu32;
  typedef unsigned int __attribute__((address_space(3))) lu32;
  __builtin_amdgcn_global_load_lds((const gu32*)gsrc_lane, (lu32*)ldsbase, 16, 0, 0);
#else
  *(uint4*)(ldsbase + ln * 16) = *(const uint4*)gsrc_lane;
#endif
}

// ==================================================================
// K-order: TAP-MAJOR — FROZEN. conv1 bitwise = r5-r18 lineage.
// r19: prep kernels fused (bodies verbatim); nmsbit 4-wave
// (identical decisions, parallel apply).
// ==================================================================

// ------------------------------------------------------------------
// Fused prep: blocks [0,512) w1pack | [512,20512) fsplit |
// [20512,20620) wtpack. Bodies verbatim from r18 (bitwise outputs).
// ------------------------------------------------------------------
__global__ __launch_bounds__(256) void prep_kernel(
    const float* __restrict__ W1, unsigned* __restrict__ W1pack,
    const float* __restrict__ feat, unsigned* __restrict__ featH,
    unsigned* __restrict__ featM, unsigned* __restrict__ featL,
    const float* __restrict__ Wreg, const float* __restrict__ Wcls,
    float* __restrict__ Wt) {
  const int bid = blockIdx.x;
  if (bid < 512) {
    int g = bid * 256 + threadIdx.x;
    int oc = g >> 8;
    int cp = g & 255;
    int cin = cp * 2;
    int ct = oc >> 7;
    int row = oc & 127;
    float buf[18];
    const float* src = W1 + (size_t)oc * 4608 + cin * 9;
    #pragma unroll
    for (int i = 0; i < 18; ++i) buf[i] = src[i];
    int k = cin & 31;
    int R = row >> 1;
    int val = ((row & 1) << 6) | (k << 1);
    int tb = (R << 7) | (val ^ ((R & 7) << 4));
    int dwimg = tb >> 2;
    int sBase = cp >> 4;
    #pragma unroll
    for (int tap = 0; tap < 9; ++tap) {
      float w0 = buf[tap], w1 = buf[9 + tap];
      unsigned short h0 = bf16_rne(w0), h1 = bf16_rne(w1);
      float r0 = w0 - bf16_f(h0), r1 = w1 - bf16_f(h1);
      unsigned short m0 = bf16_rne(r0), m1 = bf16_rne(r1);
      unsigned short l0 = bf16_rne(r0 - bf16_f(m0)), l1 = bf16_rne(r1 - bf16_f(m1));
      int s = tap * 16 + sBase;               // tap-major (frozen)
      size_t base = ((size_t)(ct * 144 + s) * 3) * 2048 + dwimg;
      W1pack[base]        = (unsigned)h0 | ((unsigned)h1 << 16);
      W1pack[base + 2048] = (unsigned)m0 | ((unsigned)m1 << 16);
      W1pack[base + 4096] = (unsigned)l0 | ((unsigned)l1 << 16);
    }
  } else if (bid < 20512) {
    int g = (bid - 512) * 256 + threadIdx.x;
    int pix = g % 2500;
    int rest = g / 2500;
    const float* fb = feat + (size_t)rest * 2 * 2500 + pix;
    float v0 = fb[0];
    float v1 = fb[2500];
    unsigned short h0 = bf16_rne(v0), h1 = bf16_rne(v1);
    float r0 = v0 - bf16_f(h0), r1 = v1 - bf16_f(h1);
    unsigned short m0 = bf16_rne(r0), m1 = bf16_rne(r1);
    unsigned short l0 = bf16_rne(r0 - bf16_f(m0)), l1 = bf16_rne(r1 - bf16_f(m1));
    featH[g] = (unsigned)h0 | ((unsigned)h1 << 16);
    featM[g] = (unsigned)m0 | ((unsigned)m1 << 16);
    featL[g] = (unsigned)l0 | ((unsigned)l1 << 16);
  } else {
    int i = (bid - 20512) * 256 + threadIdx.x;
    int gg = i / 216;
    int r  = i - gg * 216;
    int j  = r >> 2;
    int c  = gg * 4 + (r & 3);
    Wt[i] = (j < 36) ? Wreg[j * 512 + c] : Wcls[(j - 36) * 512 + c];
  }
}

// ------------------------------------------------------------------
// Conv (pre-split B) — verbatim r18, verified (666 us, bitwise).
// ------------------------------------------------------------------
__global__ __launch_bounds__(256) void conv_mfma_pre_kernel(
    const unsigned* __restrict__ featH, const unsigned* __restrict__ featM,
    const unsigned* __restrict__ featL, const char* __restrict__ W1pack,
    const float* __restrict__ b1, float* __restrict__ conv1) {
  __shared__ char smem[49152];
  const int tid = threadIdx.x;
  const int b  = blockIdx.z;
  const int ct = blockIdx.y;
  const int n0 = blockIdx.x * 128;
  const int wv = tid >> 6, ln = tid & 63;

  const int spix = tid & 127;
  const int kh   = tid >> 7;
  int p = n0 + spix; if (p > 2499) p = 2499;
  const int pyy = p / 50;
  const int pxx = p - pyy * 50;
  const unsigned* fhb = featH + (size_t)b * 256 * 2500;
  const unsigned* fmb = featM + (size_t)b * 256 * 2500;
  const unsigned* flb = featL + (size_t)b * 256 * 2500;
  const char* wsrc = W1pack + (size_t)ct * 144 * 24576;

  const int wch0  = (wv >> 1) * 64;
  const int wpix0 = (wv & 1) * 64;
  const int lrow = ln & 15, lg = ln >> 4;

  f32x4 acc[4][4];
  #pragma unroll
  for (int i = 0; i < 4; ++i)
    #pragma unroll
    for (int j = 0; j < 4; ++j) acc[i][j] = (f32x4)0.f;

  unsigned uh[8], um[8], ul[8];

  auto loadFeat = [&](int s) {
    int tap = s >> 4;
    int dy = tap / 3, dx = tap - dy * 3;
    int iy = pyy + dy - 1, ix = pxx + dx - 1;
    bool ok = ((unsigned)iy < 50u) && ((unsigned)ix < 50u);
    int cpb = ((s & 15) << 4) + kh * 8;
    size_t off = (size_t)cpb * 2500 + iy * 50 + ix;
    #pragma unroll
    for (int i = 0; i < 8; ++i) {
      size_t o = off + (size_t)i * 2500;
      uh[i] = ok ? fhb[o] : 0u;
      um[i] = ok ? fmb[o] : 0u;
      ul[i] = ok ? flb[o] : 0u;
    }
  };
  auto issueA = [&](int s) {
    const char* src = wsrc + (size_t)s * 24576;
    char* lbase = smem + (tid >> 6) * 1024;
    #pragma unroll
    for (int c = 0; c < 6; ++c)
      stage16(src + c * 4096 + tid * 16, lbase + c * 4096, ln);
  };
  auto writeB = [&]() {
    const int r = spix >> 1;
    const int swz = (r & 7) << 4;
    char* rowb = smem + 24576 + r * 128;
    #pragma unroll
    for (int pl = 0; pl < 3; ++pl) {
      const unsigned* sp = (pl == 0) ? uh : (pl == 1 ? um : ul);
      char* pb = rowb + pl * 8192;
      #pragma unroll
      for (int q = 0; q < 4; ++q) {
        int pre = ((spix & 1) << 6) + kh * 32 + q * 8;
        uint2 w;
        w.x = sp[2 * q];
        w.y = sp[2 * q + 1];
        *(uint2*)(pb + (pre ^ swz)) = w;
      }
    }
  };
  auto rdFrag = [&](const char* base, int row) -> short8 {
    int byte = (row >> 1) * 128 +
               ((((row & 1) << 6) + (lg << 4)) ^ (((row >> 1) & 7) << 4));
    return *(const short8*)(base + byte);
  };

  loadFeat(0);
  #pragma unroll 1
  for (int s = 0; s < 144; ++s) {
    __syncthreads();
    issueA(s);
    writeB();
    __syncthreads();
    if (s + 1 < 144) loadFeat(s + 1);
    short8 fa[3][4];
    #pragma unroll
    for (int pl = 0; pl < 3; ++pl)
      #pragma unroll
      for (int f = 0; f < 4; ++f)
        fa[pl][f] = rdFrag(smem + pl * 8192, wch0 + f * 16 + lrow);
    #pragma unroll
    for (int jb = 0; jb < 3; ++jb) {
      short8 fb[4];
      #pragma unroll
      for (int f = 0; f < 4; ++f)
        fb[f] = rdFrag(smem + 24576 + jb * 8192, wpix0 + f * 16 + lrow);
      const int na = 3 - jb;
      #pragma unroll
      for (int ap = 0; ap < 3; ++ap) {
        if (ap < na) {
          #pragma unroll
          for (int i = 0; i < 4; ++i)
            #pragma unroll
            for (int j = 0; j < 4; ++j)
              acc[i][j] = __builtin_amdgcn_mfma_f32_16x16x32_bf16(
                  fa[ap][i], fb[j], acc[i][j], 0, 0, 0);
        }
      }
    }
  }

  const int chb = ct * 128 + wch0 + lg * 4;
  #pragma unroll
  for (int i = 0; i < 4; ++i) {
    int ch = chb + i * 16;
    float4 bias = *(const float4*)&b1[ch];
    #pragma unroll
    for (int j = 0; j < 4; ++j) {
      int pix = n0 + wpix0 + j * 16 + lrow;
      if (pix < 2500) {
        float4 o;
        o.x = fmaxf(acc[i][j][0] + bias.x, 0.f);
        o.y = fmaxf(acc[i][j][1] + bias.y, 0.f);
        o.z = fmaxf(acc[i][j][2] + bias.z, 0.f);
        o.w = fmaxf(acc[i][j][3] + bias.w, 0.f);
        *(float4*)&conv1[(size_t)(b * 2500 + pix) * 512 + ch] = o;
      }
    }
  }
}

// ------------------------------------------------------------------
// Heads v3 (verbatim r16-r18, verified)
// ------------------------------------------------------------------
__global__ __launch_bounds__(256) void heads_kernel(
    const float* __restrict__ conv1, const float* __restrict__ Wt,
    const float* __restrict__ breg, const float* __restrict__ bcls,
    float* __restrict__ boxes, float* __restrict__ scores) {
  __shared__ float v[16][512];
  __shared__ float o54[16][56];
  const int tid = threadIdx.x;
  const int wvi = tid >> 6, lane = tid & 63;
  const int pix0 = blockIdx.x * 16;
  float4* vf = (float4*)v;
  const float4* src4 = (const float4*)(conv1 + (size_t)pix0 * 512);
  #pragma unroll
  for (int i = 0; i < 8; ++i) vf[i * 256 + tid] = src4[i * 256 + tid];
  __syncthreads();

  if (lane < 54) {
    float s[4][4];
    #pragma unroll
    for (int p = 0; p < 4; ++p)
      #pragma unroll
      for (int q = 0; q < 4; ++q) s[p][q] = 0.f;
    const int pl0 = wvi * 4;
    for (int c = 0; c < 512; c += 4) {
      float4 w = *(const float4*)&Wt[(c >> 2) * 216 + lane * 4];
      #pragma unroll
      for (int p = 0; p < 4; ++p) {
        s[p][0] = fmaf(v[pl0 + p][c],     w.x, s[p][0]);
        s[p][1] = fmaf(v[pl0 + p][c + 1], w.y, s[p][1]);
        s[p][2] = fmaf(v[pl0 + p][c + 2], w.z, s[p][2]);
        s[p][3] = fmaf(v[pl0 + p][c + 3], w.w, s[p][3]);
      }
    }
    float bias = (lane < 36) ? breg[lane] : bcls[lane - 36];
    #pragma unroll
    for (int p = 0; p < 4; ++p)
      o54[pl0 + p][lane] = (s[p][0] + s[p][1]) + (s[p][2] + s[p][3]) + bias;
  }
  __syncthreads();

  if (tid < 144) {
    const int pl = tid / 9;
    const int a  = tid - pl * 9;
    const int pix = pix0 + pl;
    const int b = pix / 2500;
    const int n = pix - b * 2500;
    const int y = n / 50, x = n - y * 50;
    float d0 = o54[pl][a * 4 + 0], d1 = o54[pl][a * 4 + 1];
    float d2 = o54[pl][a * 4 + 2], d3 = o54[pl][a * 4 + 3];
    float sc0 = o54[pl][36 + a * 2], sc1 = o54[pl][36 + a * 2 + 1];
    float mx = fmaxf(sc0, sc1);
    float e0 = expf(sc0 - mx), e1 = expf(sc1 - mx);
    float fg = e1 / (e0 + e1);
    const int ri = a / 3;
    const int si = a - ri * 3;
    float sv = (si == 0) ? 8.f : (si == 1 ? 16.f : 32.f);
    float sqr_r  = (ri == 0) ? 0.70710678f : (ri == 1 ? 1.f : 1.41421356f);
    float sqr_ir = (ri == 0) ? 1.41421356f : (ri == 1 ? 1.f : 0.70710678f);
    float hh = 16.f * sv * sqr_r;
    float ww = 16.f * sv * sqr_ir;
    float acy = 16.f * (float)(y + 1) - 25.f;
    float acx = 16.f * (float)(x + 1) - 25.f;
    float ay1 = acy - 0.5f * hh, ay2 = acy + 0.5f * hh;
    float ax1 = acx - 0.5f * ww, ax2 = acx + 0.5f * ww;
    float ah = ay2 - ay1, aw = ax2 - ax1;
    float cy0 = ay1 + 0.5f * ah, cx0 = ax1 + 0.5f * aw;
    float cy = d0 * ah + cy0, cx = d1 * aw + cx0;
    float bh = expf(d2) * ah, bw = expf(d3) * aw;
    float y1 = cy - 0.5f * bh, x1 = cx - 0.5f * bw;
    float y2 = cy + 0.5f * bh, x2 = cx + 0.5f * bw;
    y1 = fminf(fmaxf(y1, 0.f), 800.f); y2 = fminf(fmaxf(y2, 0.f), 800.f);
    x1 = fminf(fmaxf(x1, 0.f), 800.f); x2 = fminf(fmaxf(x2, 0.f), 800.f);
    bool ok = ((y2 - y1) >= 16.f) && ((x2 - x1) >= 16.f);
    int gi = b * 22500 + n * 9 + a;
    ((float4*)boxes)[gi] = make_float4(y1, x1, y2, x2);
    scores[gi] = (ok && fg == fg) ? fg : NEGV;
  }
}

// ------------------------------------------------------------------
// Top-6000 radix select — per-wave histograms (verbatim r15-r18)
// ------------------------------------------------------------------
__global__ __launch_bounds__(1024) void topk_kernel(
    const float* __restrict__ scores, const float* __restrict__ boxes,
    float* __restrict__ tsc, float* __restrict__ tbx, int* __restrict__ tidx) {
  const int b = blockIdx.x, tid = threadIdx.x;
  __shared__ unsigned hist[16][256];
  __shared__ unsigned long long sh_pref;
  __shared__ unsigned sh_rem, sh_cnt;
  const int wid = tid >> 6;
  const float* sc = scores + b * 22500;
  if (tid == 0) { sh_pref = 0ull; sh_rem = 6000u; }
  __syncthreads();
  for (int pass = 0; pass < 6; ++pass) {
    const int shift = 40 - pass * 8;
    #pragma unroll
    for (int i = tid; i < 4096; i += 1024) ((unsigned*)hist)[i] = 0u;
    __syncthreads();
    const unsigned long long pref = sh_pref;
    for (int j = tid; j < 22500; j += 1024) {
      unsigned long long key = key48(sc[j], j);
      if ((key >> (shift + 8)) == pref)
        atomicAdd(&hist[wid][(unsigned)(key >> shift) & 255u], 1u);
    }
    __syncthreads();
    if (tid < 256) {
      unsigned s = 0;
      #pragma unroll
      for (int w = 0; w < 16; ++w) s += hist[w][tid];
      hist[0][tid] = s;
    }
    __syncthreads();
    if (tid == 0) {
      unsigned rem = sh_rem;
      unsigned c = 0; int sel = 0;
      for (int bin = 255; bin >= 0; --bin) {
        unsigned nc = c + hist[0][bin];
        if (nc >= rem) { sel = bin; break; }
        c = nc;
      }
      sh_rem = rem - c;
      sh_pref = (sh_pref << 8) | (unsigned long long)sel;
    }
    __syncthreads();
  }
  const unsigned long long T = sh_pref;
  if (tid == 0) sh_cnt = 0u;
  __syncthreads();
  const float4* bx4 = (const float4*)boxes;
  float4* tb4 = (float4*)tbx;
  for (int j = tid; j < 22500; j += 1024) {
    unsigned long long key = key48(sc[j], j);
    if (key >= T) {
      unsigned slot = atomicAdd(&sh_cnt, 1u);
      if (slot < 6000u) {
        tsc[b * 6000 + slot] = sc[j];
        tidx[b * 6000 + slot] = j;
        tb4[b * 6000 + slot] = bx4[b * 22500 + j];
      }
    }
  }
}

// ------------------------------------------------------------------
// Rank-sort v2 (verbatim r16-r18, verified)
// ------------------------------------------------------------------
__global__ __launch_bounds__(256) void rank_kernel(
    const float* __restrict__ tsc, const int* __restrict__ tidx,
    const float* __restrict__ tbx,
    float* __restrict__ sbx, float* __restrict__ ssc) {
  __shared__ unsigned long long keys[6000];
  const int b = blockIdx.y;
  const int tid = threadIdx.x;
  const int c = blockIdx.x * 256 + tid;
  const float* scb = tsc + b * 6000;
  const int* idb = tidx + b * 6000;
  for (int j = tid; j < 6000; j += 256)
    keys[j] = key48(scb[j], idb[j]);
  __syncthreads();
  unsigned long long kc = (c < 6000) ? keys[c] : ~0ull;
  int rank = 0;
  #pragma unroll 4
  for (int j = 0; j < 6000; ++j)
    rank += (keys[j] > kc) ? 1 : 0;
  if (c < 6000) {
    ((float4*)sbx)[b * 6000 + rank] = ((const float4*)tbx)[b * 6000 + c];
    ssc[b * 6000 + rank] = scb[c];
  }
}

// ------------------------------------------------------------------
// Suppression bitmask — TRIANGLE (verbatim r17/r18, verified)
// ------------------------------------------------------------------
__global__ __launch_bounds__(256) void mask_kernel(
    const float* __restrict__ sbx, unsigned long long* __restrict__ mask) {
  const int b = blockIdx.y;
  const int c0 = blockIdx.x;
  const int row = c0 * 64 + (threadIdx.x & 63);
  const int wseg = threadIdx.x >> 6;
  __shared__ float4 jb[512];
  const float4* sb4 = (const float4*)sbx + (size_t)b * 6000;
  float4 rb = sb4[row < 6000 ? row : 5999];
  const float ra = (rb.z - rb.x) * (rb.w - rb.y);
  unsigned long long m[24];
  #pragma unroll
  for (int q = 0; q < 24; ++q) m[q] = 0ull;
  const int jt0 = c0 >> 3;
  for (int jt = jt0; jt < 12; ++jt) {
    __syncthreads();
    for (int s = threadIdx.x; s < 512; s += 256) {
      int j = jt * 512 + s;
      jb[s] = (j < 6000) ? sb4[j] : make_float4(0.f, 0.f, 0.f, 0.f);
    }
    __syncthreads();
    #pragma unroll
    for (int ww = 0; ww < 2; ++ww) {
      int w = jt * 8 + wseg * 2 + ww;
      if (w >= 94 || w < c0) continue;
      int j0 = (wseg * 2 + ww) * 64;
      unsigned long long bits = 0ull;
      #pragma unroll
      for (int u = 0; u < 64; ++u) {
        float4 bb = jb[j0 + u];
        float aj = (bb.z - bb.x) * (bb.w - bb.y);
        float yy1 = fmaxf(rb.x, bb.x), xx1 = fmaxf(rb.y, bb.y);
        float yy2 = fminf(rb.z, bb.z), xx2 = fminf(rb.w, bb.w);
        float inter = fmaxf(yy2 - yy1, 0.f) * fmaxf(xx2 - xx1, 0.f);
        float iou = inter / (((ra + aj) - inter) + 1e-9f);
        bits |= (iou > 0.7f) ? (1ull << u) : 0ull;
      }
      m[jt * 2 + ww] = bits;
    }
  }
  if (row < 6000) {
    unsigned long long* mr = mask + (size_t)(b * 6000 + row) * 94;
    #pragma unroll
    for (int jt = 0; jt < 12; ++jt)
      #pragma unroll
      for (int ww = 0; ww < 2; ++ww) {
        int w = jt * 8 + wseg * 2 + ww;
        if (w < 94 && w >= c0) mr[w] = m[jt * 2 + ww];
      }
  }
}

// ------------------------------------------------------------------
// Greedy bitmask walk v3: 256 threads. All 4 waves run the identical
// in-register greedy (same live[c]/dw inputs -> same decisions);
// apply assigns one word per thread (tid<94) with 4-row ILP.
// Barriers: [read live/dw] -> greedy -> barrier -> apply -> barrier.
// Pick sequence provably identical to r17/r18.
// ------------------------------------------------------------------
__global__ __launch_bounds__(256) void nmsbit_kernel(
    const float* __restrict__ ssc, const float* __restrict__ sbx,
    const unsigned long long* __restrict__ mask, float* __restrict__ out) {
  const int b = blockIdx.x, tid = threadIdx.x;
  const int lane = tid & 63;
  __shared__ unsigned long long live[94];
  __shared__ int picks[300];
  __shared__ int red[4];
  const unsigned long long* mbase = mask + (size_t)b * 6000 * 94;
  int cnt = 0;
  for (int j = tid; j < 6000; j += 256)
    cnt += (ssc[b * 6000 + j] > NEGH) ? 1 : 0;
  #pragma unroll
  for (int off = 32; off > 0; off >>= 1) cnt += __shfl_down(cnt, off);
  if (lane == 0) red[tid >> 6] = cnt;
  __syncthreads();
  const int nvalid = red[0] + red[1] + red[2] + red[3];
  for (int w = tid; w < 94; w += 256) {
    int base = w * 64;
    unsigned long long mm;
    if (base + 64 <= nvalid) mm = ~0ull;
    else if (base >= nvalid) mm = 0ull;
    else mm = (~0ull) >> (64 - (nvalid - base));
    live[w] = mm;
  }
  __syncthreads();

  int np = 0;
  for (int c = 0; c < 94 && np < 300; ++c) {
    unsigned long long bits = live[c];   // uniform: all threads read post-barrier
    if (bits == 0ull) continue;
    int row = c * 64 + lane;             // each wave holds the same 64 rows
    unsigned long long dw = (row < 6000) ? mbase[(size_t)row * 94 + c] : 0ull;
    unsigned long long prows = 0ull;
    while (bits != 0ull && np < 300) {   // identical evolution in every wave
      int bpos = __ffsll(bits) - 1;
      if (tid == 0) picks[np] = c * 64 + bpos;
      np++;
      prows |= (1ull << bpos);
      unsigned long long dwb = __shfl(dw, bpos);
      bits &= ~dwb;
      bits &= ~(1ull << bpos);
    }
    __syncthreads();                     // all reads of live/dw done before writes
    if (tid < 94 && tid >= c) {          // one word per thread, triangle guard
      unsigned long long acc = 0ull;
      unsigned long long pr = prows;
      while (pr != 0ull) {
        int r0, r1 = -1, r2 = -1, r3 = -1;
        r0 = __ffsll(pr) - 1; pr &= pr - 1ull;
        if (pr) { r1 = __ffsll(pr) - 1; pr &= pr - 1ull; }
        if (r1 >= 0 && pr) { r2 = __ffsll(pr) - 1; pr &= pr - 1ull; }
        if (r2 >= 0 && pr) { r3 = __ffsll(pr) - 1; pr &= pr - 1ull; }
        unsigned long long a0 = mbase[(size_t)(c * 64 + r0) * 94 + tid];
        unsigned long long b0 = (r1 >= 0) ? mbase[(size_t)(c * 64 + r1) * 94 + tid] : 0ull;
        unsigned long long c0 = (r2 >= 0) ? mbase[(size_t)(c * 64 + r2) * 94 + tid] : 0ull;
        unsigned long long d0 = (r3 >= 0) ? mbase[(size_t)(c * 64 + r3) * 94 + tid] : 0ull;
        acc |= (a0 | b0) | (c0 | d0);
      }
      live[tid] &= ~acc;
    }
    __syncthreads();                     // apply visible before next chunk
  }
  __syncthreads();

  float* rois = out;
  float* rsc  = out + 12000;
  for (int t = tid; t < 300; t += 256) {
    float* rp = rois + (size_t)(b * 300 + t) * 5;
    if (t < np) {
      int i = picks[t];
      float4 bb = ((const float4*)sbx)[b * 6000 + i];
      rp[0] = (float)b; rp[1] = bb.x; rp[2] = bb.y; rp[3] = bb.z; rp[4] = bb.w;
      rsc[b * 300 + t] = ssc[b * 6000 + i];
    } else {
      rp[0] = 0.f; rp[1] = 0.f; rp[2] = 0.f; rp[3] = 0.f; rp[4] = 0.f;
      rsc[b * 300 + t] = 0.f;
    }
  }
}

// ------------------------------------------------------------------
// Conv (verbatim r17 frozen) + full r17 tail for small-ws fallback.
// ------------------------------------------------------------------
__global__ __launch_bounds__(256) void conv_mfma_kernel(
    const float* __restrict__ feat, const char* __restrict__ W1pack,
    const float* __restrict__ b1, float* __restrict__ conv1) {
  __shared__ char smem[49152];
  const int tid = threadIdx.x;
  const int b  = blockIdx.z;
  const int ct = blockIdx.y;
  const int n0 = blockIdx.x * 128;
  const int wv = tid >> 6, ln = tid & 63;
  const int spix = tid & 127;
  const int kh   = tid >> 7;
  int p = n0 + spix; if (p > 2499) p = 2499;
  const int pyy = p / 50;
  const int pxx = p - pyy * 50;
  const float* featb = feat + (size_t)b * 512 * 2500;
  const char* wsrc = W1pack + (size_t)ct * 144 * 24576;
  const int wch0  = (wv >> 1) * 64;
  const int wpix0 = (wv & 1) * 64;
  const int lrow = ln & 15, lg = ln >> 4;
  f32x4 acc[4][4];
  #pragma unroll
  for (int i = 0; i < 4; ++i)
    #pragma unroll
    for (int j = 0; j < 4; ++j) acc[i][j] = (f32x4)0.f;
  float u[16];
  auto loadFeat = [&](int s) {
    int tap = s >> 4;
    int dy = tap / 3, dx = tap - dy * 3;
    int iy = pyy + dy - 1, ix = pxx + dx - 1;
    bool ok = ((unsigned)iy < 50u) && ((unsigned)ix < 50u);
    int cinb = ((s & 15) << 5) + kh * 16;
    const float* base = featb + (size_t)cinb * 2500 + iy * 50 + ix;
    #pragma unroll
    for (int i = 0; i < 16; ++i) u[i] = ok ? base[(size_t)i * 2500] : 0.f;
  };
  auto issueA = [&](int s) {
    const char* src = wsrc + (size_t)s * 24576;
    char* lbase = smem + (tid >> 6) * 1024;
    #pragma unroll
    for (int c = 0; c < 6; ++c)
      stage16(src + c * 4096 + tid * 16, lbase + c * 4096, ln);
  };
  auto writeB = [&]() {
    unsigned short h[16], m[16], l[16];
    #pragma unroll
    for (int i = 0; i < 16; ++i) {
      float v = u[i];
      h[i] = bf16_rne(v);
      float r1 = v - bf16_f(h[i]);
      m[i] = bf16_rne(r1);
      float r2 = r1 - bf16_f(m[i]);
      l[i] = bf16_rne(r2);
    }
    const int r = spix >> 1;
    const int swz = (r & 7) << 4;
    char* rowb = smem + 24576 + r * 128;
    #pragma unroll
    for (int pl = 0; pl < 3; ++pl) {
      const unsigned short* sp = (pl == 0) ? h : (pl == 1 ? m : l);
      char* pb = rowb + pl * 8192;
      #pragma unroll
      for (int q = 0; q < 4; ++q) {
        int pre = ((spix & 1) << 6) + kh * 32 + q * 8;
        uint2 w;
        w.x = (unsigned)sp[q*4]   | ((unsigned)sp[q*4+1] << 16);
        w.y = (unsigned)sp[q*4+2] | ((unsigned)sp[q*4+3] << 16);
        *(uint2*)(pb + (pre ^ swz)) = w;
      }
    }
  };
  auto rdFrag = [&](const char* base, int row) -> short8 {
    int byte = (row >> 1) * 128 +
               ((((row & 1) << 6) + (lg << 4)) ^ (((row >> 1) & 7) << 4));
    return *(const short8*)(base + byte);
  };
  loadFeat(0);
  #pragma unroll 1
  for (int s = 0; s < 144; ++s) {
    __syncthreads();
    issueA(s);
    writeB();
    __syncthreads();
    if (s + 1 < 144) loadFeat(s + 1);
    short8 fa[3][4];
    #pragma unroll
    for (int pl = 0; pl < 3; ++pl)
      #pragma unroll
      for (int f = 0; f < 4; ++f)
        fa[pl][f] = rdFrag(smem + pl * 8192, wch0 + f * 16 + lrow);
    #pragma unroll
    for (int jb = 0; jb < 3; ++jb) {
      short8 fb[4];
      #pragma unroll
      for (int f = 0; f < 4; ++f)
        fb[f] = rdFrag(smem + 24576 + jb * 8192, wpix0 + f * 16 + lrow);
      const int na = 3 - jb;
      #pragma unroll
      for (int ap = 0; ap < 3; ++ap) {
        if (ap < na) {
          #pragma unroll
          for (int i = 0; i < 4; ++i)
            #pragma unroll
            for (int j = 0; j < 4; ++j)
              acc[i][j] = __builtin_amdgcn_mfma_f32_16x16x32_bf16(
                  fa[ap][i], fb[j], acc[i][j], 0, 0, 0);
        }
      }
    }
  }
  const int chb = ct * 128 + wch0 + lg * 4;
  #pragma unroll
  for (int i = 0; i < 4; ++i) {
    int ch = chb + i * 16;
    float4 bias = *(const float4*)&b1[ch];
    #pragma unroll
    for (int j = 0; j < 4; ++j) {
      int pix = n0 + wpix0 + j * 16 + lrow;
      if (pix < 2500) {
        float4 o;
        o.x = fmaxf(acc[i][j][0] + bias.x, 0.f);
        o.y = fmaxf(acc[i][j][1] + bias.y, 0.f);
        o.z = fmaxf(acc[i][j][2] + bias.z, 0.f);
        o.w = fmaxf(acc[i][j][3] + bias.w, 0.f);
        *(float4*)&conv1[(size_t)(b * 2500 + pix) * 512 + ch] = o;
      }
    }
  }
}

__global__ __launch_bounds__(256) void w1pack_kernel(
    const float* __restrict__ W1, unsigned* __restrict__ W1pack) {
  int g = blockIdx.x * 256 + threadIdx.x;
  int oc = g >> 8;
  int cp = g & 255;
  int cin = cp * 2;
  int ct = oc >> 7;
  int row = oc & 127;
  float buf[18];
  const float* src = W1 + (size_t)oc * 4608 + cin * 9;
  #pragma unroll
  for (int i = 0; i < 18; ++i) buf[i] = src[i];
  int k = cin & 31;
  int R = row >> 1;
  int val = ((row & 1) << 6) | (k << 1);
  int tb = (R << 7) | (val ^ ((R & 7) << 4));
  int dwimg = tb >> 2;
  int sBase = cp >> 4;
  #pragma unroll
  for (int tap = 0; tap < 9; ++tap) {
    float w0 = buf[tap], w1 = buf[9 + tap];
    unsigned short h0 = bf16_rne(w0), h1 = bf16_rne(w1);
    float r0 = w0 - bf16_f(h0), r1 = w1 - bf16_f(h1);
    unsigned short m0 = bf16_rne(r0), m1 = bf16_rne(r1);
    unsigned short l0 = bf16_rne(r0 - bf16_f(m0)), l1 = bf16_rne(r1 - bf16_f(m1));
    int s = tap * 16 + sBase;
    size_t base = ((size_t)(ct * 144 + s) * 3) * 2048 + dwimg;
    W1pack[base]        = (unsigned)h0 | ((unsigned)h1 << 16);
    W1pack[base + 2048] = (unsigned)m0 | ((unsigned)m1 << 16);
    W1pack[base + 4096] = (unsigned)l0 | ((unsigned)l1 << 16);
  }
}

__global__ __launch_bounds__(256) void wtpack_kernel(
    const float* __restrict__ Wreg, const float* __restrict__ Wcls,
    float* __restrict__ Wt) {
  int i = blockIdx.x * 256 + threadIdx.x;
  int gg = i / 216;
  int r  = i - gg * 216;
  int j  = r >> 2;
  int c  = gg * 4 + (r & 3);
  Wt[i] = (j < 36) ? Wreg[j * 512 + c] : Wcls[(j - 36) * 512 + c];
}

// ------------------------------------------------------------------
extern "C" void kernel_launch(void* const* d_in, const int* in_sizes, int n_in,
                              void* d_out, int out_size, void* d_ws, size_t ws_size,
                              hipStream_t stream) {
  const float* feat = (const float*)d_in[0];
  const float* W1   = (const float*)d_in[1];
  const float* b1   = (const float*)d_in[2];
  const float* Wreg = (const float*)d_in[3];
  const float* breg = (const float*)d_in[4];
  const float* Wcls = (const float*)d_in[5];
  const float* bcls = (const float*)d_in[6];
  float* out = (float*)d_out;
  float* ws  = (float*)d_ws;

  const size_t NEED2 = 121418368ull;   // pre-split path (proven available r18)
  const size_t NEED  = 59978368ull;    // r17 fallback
  if (ws_size >= NEED2) {
    unsigned* W1pack = (unsigned*)ws;
    unsigned* featH  = (unsigned*)(ws + 3538944);
    unsigned* featM  = (unsigned*)(ws + 8658944);
    unsigned* featL  = (unsigned*)(ws + 13778944);
    float* conv1  = ws + 18898944;
    unsigned long long* mask = (unsigned long long*)(ws + 18898944);
    float* boxes  = ws + 29138944;
    float* sbx    = ws + 29138944;
    float* ssc    = ws + 29330944;
    float* scores = ws + 29858944;
    float* tbx    = ws + 30038944;
    float* tsc    = ws + 30230944;
    int*   tidx   = (int*)(ws + 30278944);
    float* Wt     = ws + 30326944;

    prep_kernel<<<20620, 256, 0, stream>>>(W1, W1pack, feat, featH, featM, featL,
                                           Wreg, Wcls, Wt);
    conv_mfma_pre_kernel<<<dim3(20, 4, 8), 256, 0, stream>>>(
        featH, featM, featL, (const char*)W1pack, b1, conv1);
    heads_kernel<<<1250, 256, 0, stream>>>(conv1, Wt, breg, bcls, boxes, scores);
    topk_kernel<<<8, 1024, 0, stream>>>(scores, boxes, tsc, tbx, tidx);
    rank_kernel<<<dim3(24, 8), 256, 0, stream>>>(tsc, tidx, tbx, sbx, ssc);
    mask_kernel<<<dim3(94, 8), 256, 0, stream>>>(sbx, mask);
    nmsbit_kernel<<<8, 256, 0, stream>>>(ssc, sbx, mask, out);
  } else if (ws_size >= NEED) {
    unsigned* W1pack = (unsigned*)ws;
    float* conv1  = ws + 3538944;
    unsigned long long* mask = (unsigned long long*)(ws + 3538944);
    float* boxes  = ws + 13778944;
    float* sbx    = ws + 13778944;
    float* ssc    = ws + 13970944;
    float* scores = ws + 14498944;
    float* tbx    = ws + 14678944;
    float* tsc    = ws + 14870944;
    int*   tidx   = (int*)(ws + 14918944);
    float* Wt     = ws + 14966944;

    w1pack_kernel<<<512, 256, 0, stream>>>(W1, W1pack);
    wtpack_kernel<<<108, 256, 0, stream>>>(Wreg, Wcls, Wt);
    conv_mfma_kernel<<<dim3(20, 4, 8), 256, 0, stream>>>(feat, (const char*)W1pack, b1, conv1);
    heads_kernel<<<1250, 256, 0, stream>>>(conv1, Wt, breg, bcls, boxes, scores);
    topk_kernel<<<8, 1024, 0, stream>>>(scores, boxes, tsc, tbx, tidx);
    rank_kernel<<<dim3(24, 8), 256, 0, stream>>>(tsc, tidx, tbx, sbx, ssc);
    mask_kernel<<<dim3(94, 8), 256, 0, stream>>>(sbx, mask);
    nmsbit_kernel<<<8, 256, 0, stream>>>(ssc, sbx, mask, out);
  }
}